// Round 1
// baseline (2535.016 us; speedup 1.0000x reference)
//
#include <hip/hip_runtime.h>
#include <math.h>

static constexpr int NNODES = 50000;
static constexpr int NEDGES = 800000;

// ---------------- gcn_norm ----------------

__global__ void deg_kernel(const int* __restrict__ col, const float* __restrict__ w,
                           float* __restrict__ deg, int e_cnt) {
  int i = blockIdx.x * 256 + threadIdx.x;
  if (i < e_cnt) unsafeAtomicAdd(&deg[col[i]], w[i]);
}

__global__ void dinv_kernel(const float* __restrict__ deg, float* __restrict__ dinv, int n) {
  int i = blockIdx.x * 256 + threadIdx.x;
  if (i < n) {
    float d = deg[i] + 1.0f;  // self-loop weight 1.0; always > 0
    dinv[i] = 1.0f / sqrtf(d);
  }
}

__global__ void norm_kernel(const int* __restrict__ row, const int* __restrict__ col,
                            const float* __restrict__ w, const float* __restrict__ dinv,
                            float* __restrict__ nrm, int e_cnt) {
  int i = blockIdx.x * 256 + threadIdx.x;
  if (i < e_cnt) nrm[i] = dinv[row[i]] * w[i] * dinv[col[i]];
}

// ---------------- dense linear: H[n][C] = X[n][K] @ W[K][C] ----------------
// 256 threads/block, 64 rows/block. W k-tile (64 x C) staged in LDS.
// Threads grouped by row: c = tid % C, group g = tid / C; x loads are
// wave-uniform (broadcast); W reads from LDS stride-1 across lanes.

template <int K, int C>
__global__ __launch_bounds__(256) void gemm_kernel(const float* __restrict__ X,
                                                   const float* __restrict__ W,
                                                   float* __restrict__ H, int n) {
  constexpr int GROUPS = 256 / C;   // 2 for C=128, 4 for C=64
  constexpr int RPT = 64 / GROUPS;  // rows per thread: 32 or 16
  constexpr int KT = K / 64;
  __shared__ float Wlds[64 * C];
  const int tid = threadIdx.x;
  const int c = tid % C;
  const int g = tid / C;
  const int rowbase = blockIdx.x * 64;
  float acc[RPT];
#pragma unroll
  for (int i = 0; i < RPT; ++i) acc[i] = 0.f;
  const bool full = (rowbase + 64 <= n);
  const float4* X4 = (const float4*)X;
  for (int kt = 0; kt < KT; ++kt) {
    const float4* Wg = (const float4*)(W + kt * 64 * C);
    float4* Wl = (float4*)Wlds;
#pragma unroll
    for (int j = 0; j < (64 * C / 4) / 256; ++j) Wl[j * 256 + tid] = Wg[j * 256 + tid];
    __syncthreads();
    if (full) {
#pragma unroll 4
      for (int k4 = 0; k4 < 16; ++k4) {
        float w0 = Wlds[(k4 * 4 + 0) * C + c];
        float w1 = Wlds[(k4 * 4 + 1) * C + c];
        float w2 = Wlds[(k4 * 4 + 2) * C + c];
        float w3 = Wlds[(k4 * 4 + 3) * C + c];
#pragma unroll
        for (int i = 0; i < RPT; ++i) {
          int r = rowbase + g + GROUPS * i;
          float4 xv = X4[(size_t)r * (K / 4) + kt * 16 + k4];
          acc[i] += xv.x * w0 + xv.y * w1 + xv.z * w2 + xv.w * w3;
        }
      }
    } else {
      for (int k4 = 0; k4 < 16; ++k4) {
        float w0 = Wlds[(k4 * 4 + 0) * C + c];
        float w1 = Wlds[(k4 * 4 + 1) * C + c];
        float w2 = Wlds[(k4 * 4 + 2) * C + c];
        float w3 = Wlds[(k4 * 4 + 3) * C + c];
        for (int i = 0; i < RPT; ++i) {
          int r = rowbase + g + GROUPS * i;
          if (r < n) {
            float4 xv = X4[(size_t)r * (K / 4) + kt * 16 + k4];
            acc[i] += xv.x * w0 + xv.y * w1 + xv.z * w2 + xv.w * w3;
          }
        }
      }
    }
    __syncthreads();
  }
#pragma unroll
  for (int i = 0; i < RPT; ++i) {
    int r = rowbase + g + GROUPS * i;
    if (r < n) H[(size_t)r * C + c] = acc[i];
  }
}

// ---------------- aggregation helpers ----------------
// CQ = channels/4 (float4 quads per row)

// agg[i][:] = h[i][:] * dinv[i]^2   (self-loop contribution as initializer)
template <int CQ>
__global__ void scale_kernel(const float* __restrict__ h, const float* __restrict__ dinv,
                             float* __restrict__ agg, int n) {
  int idx = blockIdx.x * 256 + threadIdx.x;
  if (idx < n * CQ) {
    int i = idx / CQ;
    float s = dinv[i];
    s = s * s;
    float4 v = ((const float4*)h)[idx];
    ((float4*)agg)[idx] = make_float4(v.x * s, v.y * s, v.z * s, v.w * s);
  }
}

// out[i][:] = h[i][:] * dinv[i]^2 + b[:]   (self-loop + final bias)
template <int CQ>
__global__ void scale_bias_kernel(const float* __restrict__ h, const float* __restrict__ dinv,
                                  const float* __restrict__ b, float* __restrict__ outp, int n) {
  int idx = blockIdx.x * 256 + threadIdx.x;
  if (idx < n * CQ) {
    int i = idx / CQ, c4 = idx % CQ;
    float s = dinv[i];
    s = s * s;
    float4 v = ((const float4*)h)[idx];
    float4 bv = ((const float4*)b)[c4];
    ((float4*)outp)[idx] =
        make_float4(v.x * s + bv.x, v.y * s + bv.y, v.z * s + bv.z, v.w * s + bv.w);
  }
}

// hr[i][:] = relu(agg[i][:] + b[:])
template <int CQ>
__global__ void bias_relu_kernel(const float* __restrict__ agg, const float* __restrict__ b,
                                 float* __restrict__ hr, int n) {
  int idx = blockIdx.x * 256 + threadIdx.x;
  if (idx < n * CQ) {
    int c4 = idx % CQ;
    float4 v = ((const float4*)agg)[idx];
    float4 bv = ((const float4*)b)[c4];
    ((float4*)hr)[idx] = make_float4(fmaxf(v.x + bv.x, 0.f), fmaxf(v.y + bv.y, 0.f),
                                     fmaxf(v.z + bv.z, 0.f), fmaxf(v.w + bv.w, 0.f));
  }
}

// per-edge: agg[col[e]][:] += h[row[e]][:] * norm[e]  (CQ threads per edge, 4 ch each)
template <int CQ>
__global__ void scatter_kernel(const int* __restrict__ row, const int* __restrict__ col,
                               const float* __restrict__ nrm, const float* __restrict__ h,
                               float* __restrict__ agg, int e_cnt) {
  int idx = blockIdx.x * 256 + threadIdx.x;
  int e = idx / CQ, q = idx % CQ;
  if (e < e_cnt) {
    int r = row[e], d = col[e];
    float nv = nrm[e];
    float4 hv = ((const float4*)h)[(size_t)r * CQ + q];
    float* dst = agg + ((size_t)d * CQ + q) * 4;
    unsafeAtomicAdd(dst + 0, hv.x * nv);
    unsafeAtomicAdd(dst + 1, hv.y * nv);
    unsafeAtomicAdd(dst + 2, hv.z * nv);
    unsafeAtomicAdd(dst + 3, hv.w * nv);
  }
}

// ---------------- launch ----------------

extern "C" void kernel_launch(void* const* d_in, const int* in_sizes, int n_in,
                              void* d_out, int out_size, void* d_ws, size_t ws_size,
                              hipStream_t stream) {
  const float* x = (const float*)d_in[0];
  const int* ei = (const int*)d_in[1];
  const float* ew = (const float*)d_in[2];
  const float* W1 = (const float*)d_in[3];
  const float* b1 = (const float*)d_in[4];
  const float* W2 = (const float*)d_in[5];
  const float* b2 = (const float*)d_in[6];
  float* outp = (float*)d_out;

  const int N = NNODES, E = NEDGES;
  const int* rowp = ei;
  const int* colp = ei + E;

  float* ws = (float*)d_ws;
  float* deg = ws;                          // N
  float* dinv = deg + N;                    // N
  float* nrm = dinv + N;                    // E
  float* h1 = nrm + E;                      // N*128 (later reused as relu'd hidden)
  float* agg1 = h1 + (size_t)N * 128;       // N*128
  float* h2 = agg1 + (size_t)N * 128;       // N*64

  hipMemsetAsync(deg, 0, (size_t)N * sizeof(float), stream);
  deg_kernel<<<(E + 255) / 256, 256, 0, stream>>>(colp, ew, deg, E);
  dinv_kernel<<<(N + 255) / 256, 256, 0, stream>>>(deg, dinv, N);
  norm_kernel<<<(E + 255) / 256, 256, 0, stream>>>(rowp, colp, ew, dinv, nrm, E);

  // layer 1
  gemm_kernel<256, 128><<<(N + 63) / 64, 256, 0, stream>>>(x, W1, h1, N);
  scale_kernel<32><<<(N * 32 + 255) / 256, 256, 0, stream>>>(h1, dinv, agg1, N);
  scatter_kernel<32><<<(E * 32 + 255) / 256, 256, 0, stream>>>(rowp, colp, nrm, h1, agg1, E);
  bias_relu_kernel<32><<<(N * 32 + 255) / 256, 256, 0, stream>>>(agg1, b1, h1, N);

  // layer 2
  gemm_kernel<128, 64><<<(N + 63) / 64, 256, 0, stream>>>(h1, W2, h2, N);
  scale_bias_kernel<16><<<(N * 16 + 255) / 256, 256, 0, stream>>>(h2, dinv, b2, outp, N);
  scatter_kernel<16><<<(E * 16 + 255) / 256, 256, 0, stream>>>(rowp, colp, nrm, h2, outp, E);
}

// Round 2
// 714.205 us; speedup vs baseline: 3.5494x; 3.5494x over previous
//
#include <hip/hip_runtime.h>
#include <math.h>

static constexpr int NNODES = 50000;
static constexpr int NEDGES = 800000;

// ---------------- gcn_norm ----------------

__global__ void deg_kernel(const int* __restrict__ col, const float* __restrict__ w,
                           float* __restrict__ deg, int e_cnt) {
  int i = blockIdx.x * 256 + threadIdx.x;
  if (i < e_cnt) unsafeAtomicAdd(&deg[col[i]], w[i]);
}

__global__ void dinv_kernel(const float* __restrict__ deg, float* __restrict__ dinv, int n) {
  int i = blockIdx.x * 256 + threadIdx.x;
  if (i < n) {
    float d = deg[i] + 1.0f;  // self-loop weight 1.0; always > 0
    dinv[i] = 1.0f / sqrtf(d);
  }
}

__global__ void norm_kernel(const int* __restrict__ row, const int* __restrict__ col,
                            const float* __restrict__ w, const float* __restrict__ dinv,
                            float* __restrict__ nrm, int e_cnt) {
  int i = blockIdx.x * 256 + threadIdx.x;
  if (i < e_cnt) nrm[i] = dinv[row[i]] * w[i] * dinv[col[i]];
}

// ---------------- CSR build (counting sort by dst) ----------------

__global__ void zero_int_kernel(int* __restrict__ p, int n) {
  int i = blockIdx.x * 256 + threadIdx.x;
  if (i < n) p[i] = 0;
}

__global__ void count_kernel(const int* __restrict__ col, int* __restrict__ cnt, int e_cnt) {
  int i = blockIdx.x * 256 + threadIdx.x;
  if (i < e_cnt) atomicAdd(&cnt[col[i]], 1);
}

// per-block inclusive scan -> exclusive out + block sums
__global__ void scan1_kernel(const int* __restrict__ in, int* __restrict__ excl,
                             int* __restrict__ bsum, int n) {
  __shared__ int buf[256];
  int tid = threadIdx.x;
  int i = blockIdx.x * 256 + tid;
  int v = (i < n) ? in[i] : 0;
  buf[tid] = v;
  __syncthreads();
  for (int off = 1; off < 256; off <<= 1) {
    int t = (tid >= off) ? buf[tid - off] : 0;
    __syncthreads();
    buf[tid] += t;
    __syncthreads();
  }
  if (i < n) excl[i] = buf[tid] - v;
  if (tid == 255) bsum[blockIdx.x] = buf[255];
}

// single-block exclusive scan in place (nb <= 256)
__global__ void scan2_kernel(int* __restrict__ bsum, int nb) {
  __shared__ int buf[256];
  int tid = threadIdx.x;
  int v = (tid < nb) ? bsum[tid] : 0;
  buf[tid] = v;
  __syncthreads();
  for (int off = 1; off < 256; off <<= 1) {
    int t = (tid >= off) ? buf[tid - off] : 0;
    __syncthreads();
    buf[tid] += t;
    __syncthreads();
  }
  if (tid < nb) bsum[tid] = buf[tid] - v;
}

// add block offsets; also produce cursor copy for the fill pass
__global__ void scan3_kernel(int* __restrict__ excl, const int* __restrict__ bsum,
                             int* __restrict__ cursor, int n) {
  int i = blockIdx.x * 256 + threadIdx.x;
  if (i < n) {
    int s = excl[i] + bsum[blockIdx.x];
    excl[i] = s;
    cursor[i] = s;
  }
}

__global__ void fill_kernel(const int* __restrict__ row, const int* __restrict__ col,
                            const float* __restrict__ nrm, int* __restrict__ cursor,
                            int* __restrict__ csr_src, float* __restrict__ csr_nrm, int e_cnt) {
  int i = blockIdx.x * 256 + threadIdx.x;
  if (i < e_cnt) {
    int d = col[i];
    int p = atomicAdd(&cursor[d], 1);
    csr_src[p] = row[i];
    csr_nrm[p] = nrm[i];
  }
}

// ---------------- dense linear: H[n][C] = X[n][K] @ W[K][C] ----------------

template <int K, int C>
__global__ __launch_bounds__(256) void gemm_kernel(const float* __restrict__ X,
                                                   const float* __restrict__ W,
                                                   float* __restrict__ H, int n) {
  constexpr int GROUPS = 256 / C;   // 2 for C=128, 4 for C=64
  constexpr int RPT = 64 / GROUPS;  // rows per thread: 32 or 16
  constexpr int KT = K / 64;
  __shared__ float Wlds[64 * C];
  const int tid = threadIdx.x;
  const int c = tid % C;
  const int g = tid / C;
  const int rowbase = blockIdx.x * 64;
  float acc[RPT];
#pragma unroll
  for (int i = 0; i < RPT; ++i) acc[i] = 0.f;
  const bool full = (rowbase + 64 <= n);
  const float4* X4 = (const float4*)X;
  for (int kt = 0; kt < KT; ++kt) {
    const float4* Wg = (const float4*)(W + kt * 64 * C);
    float4* Wl = (float4*)Wlds;
#pragma unroll
    for (int j = 0; j < (64 * C / 4) / 256; ++j) Wl[j * 256 + tid] = Wg[j * 256 + tid];
    __syncthreads();
    if (full) {
#pragma unroll 4
      for (int k4 = 0; k4 < 16; ++k4) {
        float w0 = Wlds[(k4 * 4 + 0) * C + c];
        float w1 = Wlds[(k4 * 4 + 1) * C + c];
        float w2 = Wlds[(k4 * 4 + 2) * C + c];
        float w3 = Wlds[(k4 * 4 + 3) * C + c];
#pragma unroll
        for (int i = 0; i < RPT; ++i) {
          int r = rowbase + g + GROUPS * i;
          float4 xv = X4[(size_t)r * (K / 4) + kt * 16 + k4];
          acc[i] += xv.x * w0 + xv.y * w1 + xv.z * w2 + xv.w * w3;
        }
      }
    } else {
      for (int k4 = 0; k4 < 16; ++k4) {
        float w0 = Wlds[(k4 * 4 + 0) * C + c];
        float w1 = Wlds[(k4 * 4 + 1) * C + c];
        float w2 = Wlds[(k4 * 4 + 2) * C + c];
        float w3 = Wlds[(k4 * 4 + 3) * C + c];
        for (int i = 0; i < RPT; ++i) {
          int r = rowbase + g + GROUPS * i;
          if (r < n) {
            float4 xv = X4[(size_t)r * (K / 4) + kt * 16 + k4];
            acc[i] += xv.x * w0 + xv.y * w1 + xv.z * w2 + xv.w * w3;
          }
        }
      }
    }
    __syncthreads();
  }
#pragma unroll
  for (int i = 0; i < RPT; ++i) {
    int r = rowbase + g + GROUPS * i;
    if (r < n) H[(size_t)r * C + c] = acc[i];
  }
}

// ---------------- fused CSR gather: out[d] = act( h[d]*dinv[d]^2 + sum_e h[src]*nrm + b ) ----
// CQ = C/4 threads per node, each handling one float4 of channels.

template <int CQ, bool RELU>
__global__ __launch_bounds__(256) void gather_kernel(
    const float* __restrict__ h, const float* __restrict__ dinv, const float* __restrict__ b,
    const int* __restrict__ start, const int* __restrict__ csr_src,
    const float* __restrict__ csr_nrm, float* __restrict__ outp, int n, int e_cnt) {
  constexpr int NPB = 256 / CQ;
  const int tid = threadIdx.x;
  const int q = tid % CQ;
  const int g = tid / CQ;
  const int d = blockIdx.x * NPB + g;
  if (d >= n) return;
  const float4* h4 = (const float4*)h;
  float s = dinv[d];
  s = s * s;
  float4 v = h4[(size_t)d * CQ + q];
  float ax = v.x * s, ay = v.y * s, az = v.z * s, aw = v.w * s;
  const int k0 = start[d];
  const int k1 = (d + 1 < n) ? start[d + 1] : e_cnt;
  for (int k = k0; k < k1; ++k) {
    int srcn = csr_src[k];
    float nv = csr_nrm[k];
    float4 hv = h4[(size_t)srcn * CQ + q];
    ax += hv.x * nv;
    ay += hv.y * nv;
    az += hv.z * nv;
    aw += hv.w * nv;
  }
  float4 bv = ((const float4*)b)[q];
  ax += bv.x;
  ay += bv.y;
  az += bv.z;
  aw += bv.w;
  if (RELU) {
    ax = fmaxf(ax, 0.f);
    ay = fmaxf(ay, 0.f);
    az = fmaxf(az, 0.f);
    aw = fmaxf(aw, 0.f);
  }
  ((float4*)outp)[(size_t)d * CQ + q] = make_float4(ax, ay, az, aw);
}

// ---------------- launch ----------------

extern "C" void kernel_launch(void* const* d_in, const int* in_sizes, int n_in,
                              void* d_out, int out_size, void* d_ws, size_t ws_size,
                              hipStream_t stream) {
  const float* x = (const float*)d_in[0];
  const int* ei = (const int*)d_in[1];
  const float* ew = (const float*)d_in[2];
  const float* W1 = (const float*)d_in[3];
  const float* b1 = (const float*)d_in[4];
  const float* W2 = (const float*)d_in[5];
  const float* b2 = (const float*)d_in[6];
  float* outp = (float*)d_out;

  const int N = NNODES, E = NEDGES;
  const int* rowp = ei;
  const int* colp = ei + E;
  const int NB = (N + 255) / 256;  // 196 scan blocks

  // workspace carve-up
  char* wsb = (char*)d_ws;
  float* deg = (float*)wsb;                      wsb += (size_t)N * 4;
  float* dinv = (float*)wsb;                     wsb += (size_t)N * 4;
  float* nrm = (float*)wsb;                      wsb += (size_t)E * 4;
  float* h1 = (float*)wsb;                       wsb += (size_t)N * 128 * 4;
  float* h1r = (float*)wsb;                      wsb += (size_t)N * 128 * 4;
  float* h2 = (float*)wsb;                       wsb += (size_t)N * 64 * 4;
  float* csr_nrm = (float*)wsb;                  wsb += (size_t)E * 4;
  int* cnt = (int*)wsb;                          wsb += (size_t)N * 4;
  int* start = (int*)wsb;                        wsb += (size_t)N * 4;
  int* cursor = (int*)wsb;                       wsb += (size_t)N * 4;
  int* bsum = (int*)wsb;                         wsb += (size_t)256 * 4;
  int* csr_src = (int*)wsb;                      wsb += (size_t)E * 4;

  // norm
  hipMemsetAsync(deg, 0, (size_t)N * sizeof(float), stream);
  deg_kernel<<<(E + 255) / 256, 256, 0, stream>>>(colp, ew, deg, E);
  dinv_kernel<<<NB, 256, 0, stream>>>(deg, dinv, N);
  norm_kernel<<<(E + 255) / 256, 256, 0, stream>>>(rowp, colp, ew, dinv, nrm, E);

  // CSR by destination
  zero_int_kernel<<<NB, 256, 0, stream>>>(cnt, N);
  count_kernel<<<(E + 255) / 256, 256, 0, stream>>>(colp, cnt, E);
  scan1_kernel<<<NB, 256, 0, stream>>>(cnt, start, bsum, N);
  scan2_kernel<<<1, 256, 0, stream>>>(bsum, NB);
  scan3_kernel<<<NB, 256, 0, stream>>>(start, bsum, cursor, N);
  fill_kernel<<<(E + 255) / 256, 256, 0, stream>>>(rowp, colp, nrm, cursor, csr_src, csr_nrm, E);

  // layer 1: GEMM + fused gather (+bias+relu)
  gemm_kernel<256, 128><<<(N + 63) / 64, 256, 0, stream>>>(x, W1, h1, N);
  gather_kernel<32, true><<<(N + 7) / 8, 256, 0, stream>>>(h1, dinv, b1, start, csr_src,
                                                           csr_nrm, h1r, N, E);

  // layer 2: GEMM + fused gather (+bias)
  gemm_kernel<128, 64><<<(N + 63) / 64, 256, 0, stream>>>(h1r, W2, h2, N);
  gather_kernel<16, false><<<(N + 15) / 16, 256, 0, stream>>>(h2, dinv, b2, start, csr_src,
                                                              csr_nrm, outp, N, E);
}

// Round 3
// 301.972 us; speedup vs baseline: 8.3949x; 2.3651x over previous
//
#include <hip/hip_runtime.h>
#include <hip/hip_bf16.h>
#include <math.h>

static constexpr int NNODES = 50000;
static constexpr int NEDGES = 800000;

typedef __attribute__((ext_vector_type(8))) short bf16x8;
typedef __attribute__((ext_vector_type(4))) float f32x4;

__device__ inline short f2bf(float f) {
  __hip_bfloat16 h = __float2bfloat16(f);
  union { __hip_bfloat16 h; short s; } u;
  u.h = h;
  return u.s;
}

// ---------------- gcn_norm ----------------

__global__ void deg_kernel(const int* __restrict__ col, const float* __restrict__ w,
                           float* __restrict__ deg, int e_cnt) {
  int i = blockIdx.x * 256 + threadIdx.x;
  if (i < e_cnt) unsafeAtomicAdd(&deg[col[i]], w[i]);
}

__global__ void dinv_kernel(const float* __restrict__ deg, float* __restrict__ dinv, int n) {
  int i = blockIdx.x * 256 + threadIdx.x;
  if (i < n) {
    float d = deg[i] + 1.0f;  // self-loop weight 1.0; always > 0
    dinv[i] = 1.0f / sqrtf(d);
  }
}

__global__ void norm_kernel(const int* __restrict__ row, const int* __restrict__ col,
                            const float* __restrict__ w, const float* __restrict__ dinv,
                            float* __restrict__ nrm, int e_cnt) {
  int i = blockIdx.x * 256 + threadIdx.x;
  if (i < e_cnt) nrm[i] = dinv[row[i]] * w[i] * dinv[col[i]];
}

// ---------------- CSR build (counting sort by dst) ----------------

__global__ void zero_int_kernel(int* __restrict__ p, int n) {
  int i = blockIdx.x * 256 + threadIdx.x;
  if (i < n) p[i] = 0;
}

__global__ void count_kernel(const int* __restrict__ col, int* __restrict__ cnt, int e_cnt) {
  int i = blockIdx.x * 256 + threadIdx.x;
  if (i < e_cnt) atomicAdd(&cnt[col[i]], 1);
}

__global__ void scan1_kernel(const int* __restrict__ in, int* __restrict__ excl,
                             int* __restrict__ bsum, int n) {
  __shared__ int buf[256];
  int tid = threadIdx.x;
  int i = blockIdx.x * 256 + tid;
  int v = (i < n) ? in[i] : 0;
  buf[tid] = v;
  __syncthreads();
  for (int off = 1; off < 256; off <<= 1) {
    int t = (tid >= off) ? buf[tid - off] : 0;
    __syncthreads();
    buf[tid] += t;
    __syncthreads();
  }
  if (i < n) excl[i] = buf[tid] - v;
  if (tid == 255) bsum[blockIdx.x] = buf[255];
}

__global__ void scan2_kernel(int* __restrict__ bsum, int nb) {
  __shared__ int buf[256];
  int tid = threadIdx.x;
  int v = (tid < nb) ? bsum[tid] : 0;
  buf[tid] = v;
  __syncthreads();
  for (int off = 1; off < 256; off <<= 1) {
    int t = (tid >= off) ? buf[tid - off] : 0;
    __syncthreads();
    buf[tid] += t;
    __syncthreads();
  }
  if (tid < nb) bsum[tid] = buf[tid] - v;
}

__global__ void scan3_kernel(int* __restrict__ excl, const int* __restrict__ bsum,
                             int* __restrict__ cursor, int n) {
  int i = blockIdx.x * 256 + threadIdx.x;
  if (i < n) {
    int s = excl[i] + bsum[blockIdx.x];
    excl[i] = s;
    cursor[i] = s;
  }
}

__global__ void fill_kernel(const int* __restrict__ row, const int* __restrict__ col,
                            const float* __restrict__ nrm, int* __restrict__ cursor,
                            int* __restrict__ csr_src, float* __restrict__ csr_nrm, int e_cnt) {
  int i = blockIdx.x * 256 + threadIdx.x;
  if (i < e_cnt) {
    int d = col[i];
    int p = atomicAdd(&cursor[d], 1);
    csr_src[p] = row[i];
    csr_nrm[p] = nrm[i];
  }
}

// ---------------- bf16 MFMA GEMM: H[n][NTOT] = X[n][K] @ W[K][NTOT] ----------------
// Block: 256 threads = 4 waves (2M x 2N). Block tile = 128 rows x NTOT cols.
// W staged ONCE into LDS (fragment-major bf16, ds_read_b128 conflict-free).
// A fragments loaded from global f32, converted to bf16 in-register.
// MFMA 16x16x32 bf16; D layout col=lane&15, row=(lane>>4)*4+reg [m89-verified].

template <int K, int NTOT>
__global__ __launch_bounds__(256) void mfma_gemm_kernel(const float* __restrict__ X,
                                                        const float* __restrict__ W,
                                                        float* __restrict__ H, int n) {
  constexpr int KF = K / 32;      // k-fragments
  constexpr int NPF = NTOT / 16;  // n-fragments per block (block covers all cols)
  constexpr int NF = NTOT / 32;   // n-fragments per wave
  __shared__ alignas(16) short Blds[KF * NPF * 64 * 8];
  const int tid = threadIdx.x;
  const int lane = tid & 63;
  const int wave = tid >> 6;
  const int lrow = lane & 15;
  const int lgrp = lane >> 4;

  // ---- stage W into LDS, fragment-major: frag f=(kf*NPF+nfb), lane-order 8 bf16 ----
  for (int f = wave; f < KF * NPF; f += 4) {
    int kf = f / NPF, nfb = f % NPF;
    int col = nfb * 16 + lrow;
    int krow = kf * 32 + lgrp * 8;
    bf16x8 bv;
#pragma unroll
    for (int i = 0; i < 8; ++i) bv[i] = f2bf(W[(size_t)(krow + i) * NTOT + col]);
    ((bf16x8*)Blds)[f * 64 + lane] = bv;
  }
  __syncthreads();

  const int wm = wave >> 1, wn = wave & 1;
  const int rowbase = blockIdx.x * 128 + wm * 64;
  const int nmax = n - 1;
  f32x4 acc[4][NF] = {};

  for (int ks = 0; ks < KF; ++ks) {
    bf16x8 af[4];
#pragma unroll
    for (int mi = 0; mi < 4; ++mi) {
      int r = rowbase + mi * 16 + lrow;
      r = r > nmax ? nmax : r;
      const float* xp = X + (size_t)r * K + ks * 32 + lgrp * 8;
      float4 x0 = *(const float4*)xp;
      float4 x1 = *(const float4*)(xp + 4);
      af[mi][0] = f2bf(x0.x);
      af[mi][1] = f2bf(x0.y);
      af[mi][2] = f2bf(x0.z);
      af[mi][3] = f2bf(x0.w);
      af[mi][4] = f2bf(x1.x);
      af[mi][5] = f2bf(x1.y);
      af[mi][6] = f2bf(x1.z);
      af[mi][7] = f2bf(x1.w);
    }
    bf16x8 bfr[NF];
#pragma unroll
    for (int nf = 0; nf < NF; ++nf)
      bfr[nf] = ((const bf16x8*)Blds)[(ks * NPF + wn * NF + nf) * 64 + lane];
#pragma unroll
    for (int mi = 0; mi < 4; ++mi)
#pragma unroll
      for (int nf = 0; nf < NF; ++nf)
        acc[mi][nf] = __builtin_amdgcn_mfma_f32_16x16x32_bf16(af[mi], bfr[nf], acc[mi][nf], 0, 0, 0);
  }

#pragma unroll
  for (int mi = 0; mi < 4; ++mi) {
    int r0 = rowbase + mi * 16 + lgrp * 4;
#pragma unroll
    for (int nf = 0; nf < NF; ++nf) {
      int col = (wn * NF + nf) * 16 + lrow;
#pragma unroll
      for (int rr = 0; rr < 4; ++rr) {
        int r = r0 + rr;
        if (r < n) H[(size_t)r * NTOT + col] = acc[mi][nf][rr];
      }
    }
  }
}

// ---------------- fused CSR gather: out[d] = act( h[d]*dinv[d]^2 + sum_e h[src]*nrm + b ) ----

template <int CQ, bool RELU>
__global__ __launch_bounds__(256) void gather_kernel(
    const float* __restrict__ h, const float* __restrict__ dinv, const float* __restrict__ b,
    const int* __restrict__ start, const int* __restrict__ csr_src,
    const float* __restrict__ csr_nrm, float* __restrict__ outp, int n, int e_cnt) {
  constexpr int NPB = 256 / CQ;
  const int tid = threadIdx.x;
  const int q = tid % CQ;
  const int g = tid / CQ;
  const int d = blockIdx.x * NPB + g;
  if (d >= n) return;
  const float4* h4 = (const float4*)h;
  float s = dinv[d];
  s = s * s;
  float4 v = h4[(size_t)d * CQ + q];
  float ax = v.x * s, ay = v.y * s, az = v.z * s, aw = v.w * s;
  const int k0 = start[d];
  const int k1 = (d + 1 < n) ? start[d + 1] : e_cnt;
  for (int k = k0; k < k1; ++k) {
    int srcn = csr_src[k];
    float nv = csr_nrm[k];
    float4 hv = h4[(size_t)srcn * CQ + q];
    ax += hv.x * nv;
    ay += hv.y * nv;
    az += hv.z * nv;
    aw += hv.w * nv;
  }
  float4 bv = ((const float4*)b)[q];
  ax += bv.x;
  ay += bv.y;
  az += bv.z;
  aw += bv.w;
  if (RELU) {
    ax = fmaxf(ax, 0.f);
    ay = fmaxf(ay, 0.f);
    az = fmaxf(az, 0.f);
    aw = fmaxf(aw, 0.f);
  }
  ((float4*)outp)[(size_t)d * CQ + q] = make_float4(ax, ay, az, aw);
}

// ---------------- launch ----------------

extern "C" void kernel_launch(void* const* d_in, const int* in_sizes, int n_in,
                              void* d_out, int out_size, void* d_ws, size_t ws_size,
                              hipStream_t stream) {
  const float* x = (const float*)d_in[0];
  const int* ei = (const int*)d_in[1];
  const float* ew = (const float*)d_in[2];
  const float* W1 = (const float*)d_in[3];
  const float* b1 = (const float*)d_in[4];
  const float* W2 = (const float*)d_in[5];
  const float* b2 = (const float*)d_in[6];
  float* outp = (float*)d_out;

  const int N = NNODES, E = NEDGES;
  const int* rowp = ei;
  const int* colp = ei + E;
  const int NB = (N + 255) / 256;

  // workspace carve-up
  char* wsb = (char*)d_ws;
  float* deg = (float*)wsb;                      wsb += (size_t)N * 4;
  float* dinv = (float*)wsb;                     wsb += (size_t)N * 4;
  float* nrm = (float*)wsb;                      wsb += (size_t)E * 4;
  float* h1 = (float*)wsb;                       wsb += (size_t)N * 128 * 4;
  float* h1r = (float*)wsb;                      wsb += (size_t)N * 128 * 4;
  float* h2 = (float*)wsb;                       wsb += (size_t)N * 64 * 4;
  float* csr_nrm = (float*)wsb;                  wsb += (size_t)E * 4;
  int* cnt = (int*)wsb;                          wsb += (size_t)N * 4;
  int* start = (int*)wsb;                        wsb += (size_t)N * 4;
  int* cursor = (int*)wsb;                       wsb += (size_t)N * 4;
  int* bsum = (int*)wsb;                         wsb += (size_t)256 * 4;
  int* csr_src = (int*)wsb;                      wsb += (size_t)E * 4;

  // norm
  hipMemsetAsync(deg, 0, (size_t)N * sizeof(float), stream);
  deg_kernel<<<(E + 255) / 256, 256, 0, stream>>>(colp, ew, deg, E);
  dinv_kernel<<<NB, 256, 0, stream>>>(deg, dinv, N);
  norm_kernel<<<(E + 255) / 256, 256, 0, stream>>>(rowp, colp, ew, dinv, nrm, E);

  // CSR by destination
  zero_int_kernel<<<NB, 256, 0, stream>>>(cnt, N);
  count_kernel<<<(E + 255) / 256, 256, 0, stream>>>(colp, cnt, E);
  scan1_kernel<<<NB, 256, 0, stream>>>(cnt, start, bsum, N);
  scan2_kernel<<<1, 256, 0, stream>>>(bsum, NB);
  scan3_kernel<<<NB, 256, 0, stream>>>(start, bsum, cursor, N);
  fill_kernel<<<(E + 255) / 256, 256, 0, stream>>>(rowp, colp, nrm, cursor, csr_src, csr_nrm, E);

  // layer 1: MFMA GEMM + fused gather (+bias+relu)
  mfma_gemm_kernel<256, 128><<<(N + 127) / 128, 256, 0, stream>>>(x, W1, h1, N);
  gather_kernel<32, true><<<(N + 7) / 8, 256, 0, stream>>>(h1, dinv, b1, start, csr_src,
                                                           csr_nrm, h1r, N, E);

  // layer 2: MFMA GEMM + fused gather (+bias)
  mfma_gemm_kernel<128, 64><<<(N + 127) / 128, 256, 0, stream>>>(h1r, W2, h2, N);
  gather_kernel<16, false><<<(N + 15) / 16, 256, 0, stream>>>(h2, dinv, b2, start, csr_src,
                                                              csr_nrm, outp, N, E);
}

// Round 4
// 238.856 us; speedup vs baseline: 10.6131x; 1.2642x over previous
//
#include <hip/hip_runtime.h>
#include <hip/hip_bf16.h>
#include <math.h>

static constexpr int NNODES = 50000;
static constexpr int NEDGES = 800000;

typedef __attribute__((ext_vector_type(8))) short bf16x8;
typedef __attribute__((ext_vector_type(4))) float f32x4;

__device__ inline short f2bf(float f) {
  union { __hip_bfloat16 h; short s; } u;
  u.h = __float2bfloat16(f);
  return u.s;
}

__device__ inline float bf2f(short s) {
  union { unsigned int u; float f; } u;
  u.u = ((unsigned int)(unsigned short)s) << 16;
  return u.f;
}

// ---------------- fused deg + count (one edge pass) ----------------

__global__ void deg_count_kernel(const int* __restrict__ col, const float* __restrict__ w,
                                 float* __restrict__ deg, int* __restrict__ cnt, int e_cnt) {
  int i = blockIdx.x * 256 + threadIdx.x;
  if (i < e_cnt) {
    int d = col[i];
    unsafeAtomicAdd(&deg[d], w[i]);
    atomicAdd(&cnt[d], 1);
  }
}

// ---------------- scans ----------------

__global__ void scan1_kernel(const int* __restrict__ in, int* __restrict__ excl,
                             int* __restrict__ bsum, int n) {
  __shared__ int buf[256];
  int tid = threadIdx.x;
  int i = blockIdx.x * 256 + tid;
  int v = (i < n) ? in[i] : 0;
  buf[tid] = v;
  __syncthreads();
  for (int off = 1; off < 256; off <<= 1) {
    int t = (tid >= off) ? buf[tid - off] : 0;
    __syncthreads();
    buf[tid] += t;
    __syncthreads();
  }
  if (i < n) excl[i] = buf[tid] - v;
  if (tid == 255) bsum[blockIdx.x] = buf[255];
}

__global__ void scan2_kernel(int* __restrict__ bsum, int nb) {
  __shared__ int buf[256];
  int tid = threadIdx.x;
  int v = (tid < nb) ? bsum[tid] : 0;
  buf[tid] = v;
  __syncthreads();
  for (int off = 1; off < 256; off <<= 1) {
    int t = (tid >= off) ? buf[tid - off] : 0;
    __syncthreads();
    buf[tid] += t;
    __syncthreads();
  }
  if (tid < nb) bsum[tid] = buf[tid] - v;
}

// add block offsets, copy to cursor, and compute dinv (fused)
__global__ void scan3_kernel(int* __restrict__ excl, const int* __restrict__ bsum,
                             int* __restrict__ cursor, const float* __restrict__ deg,
                             float* __restrict__ dinv, int n) {
  int i = blockIdx.x * 256 + threadIdx.x;
  if (i < n) {
    int s = excl[i] + bsum[blockIdx.x];
    excl[i] = s;
    cursor[i] = s;
    float d = deg[i] + 1.0f;  // self-loop weight 1.0
    dinv[i] = 1.0f / sqrtf(d);
  }
}

// ---------------- fill (norm fused in, packed int2 {src, bits(nrm)}) ----------------

__global__ void fill_kernel(const int* __restrict__ row, const int* __restrict__ col,
                            const float* __restrict__ w, const float* __restrict__ dinv,
                            int* __restrict__ cursor, int2* __restrict__ csr, int e_cnt) {
  int i = blockIdx.x * 256 + threadIdx.x;
  if (i < e_cnt) {
    int r = row[i], d = col[i];
    float nv = dinv[r] * w[i] * dinv[d];
    int p = atomicAdd(&cursor[d], 1);
    int2 e;
    e.x = r;
    union { float f; int i; } u;
    u.f = nv;
    e.y = u.i;
    csr[p] = e;
  }
}

// ---------------- bf16 MFMA GEMM: H[n][NTOT] = A[n][K] @ W[K][NTOT], H in bf16 ----------
// Block: 256 threads = 4 waves (2M x 2N). Block tile = 128 rows x NTOT cols.
// W staged ONCE into LDS (fragment-major bf16). A either f32 (converted) or bf16.
// D layout col=lane&15, row=(lane>>4)*4+reg [m89-verified].

template <int K, int NTOT, bool A_BF16>
__global__ __launch_bounds__(256) void mfma_gemm_kernel(const void* __restrict__ Av,
                                                        const float* __restrict__ W,
                                                        short* __restrict__ H, int n) {
  constexpr int KF = K / 32;
  constexpr int NPF = NTOT / 16;
  constexpr int NF = NTOT / 32;
  __shared__ alignas(16) short Blds[KF * NPF * 64 * 8];
  const int tid = threadIdx.x;
  const int lane = tid & 63;
  const int wave = tid >> 6;
  const int lrow = lane & 15;
  const int lgrp = lane >> 4;

  for (int f = wave; f < KF * NPF; f += 4) {
    int kf = f / NPF, nfb = f % NPF;
    int colc = nfb * 16 + lrow;
    int krow = kf * 32 + lgrp * 8;
    bf16x8 bv;
#pragma unroll
    for (int i = 0; i < 8; ++i) bv[i] = f2bf(W[(size_t)(krow + i) * NTOT + colc]);
    ((bf16x8*)Blds)[f * 64 + lane] = bv;
  }
  __syncthreads();

  const int wm = wave >> 1, wn = wave & 1;
  const int rowbase = blockIdx.x * 128 + wm * 64;
  const int nmax = n - 1;
  f32x4 acc[4][NF] = {};

  for (int ks = 0; ks < KF; ++ks) {
    bf16x8 af[4];
#pragma unroll
    for (int mi = 0; mi < 4; ++mi) {
      int r = rowbase + mi * 16 + lrow;
      r = r > nmax ? nmax : r;
      if (A_BF16) {
        const short* X = (const short*)Av;
        af[mi] = *(const bf16x8*)(X + (size_t)r * K + ks * 32 + lgrp * 8);
      } else {
        const float* X = (const float*)Av;
        const float* xp = X + (size_t)r * K + ks * 32 + lgrp * 8;
        float4 x0 = *(const float4*)xp;
        float4 x1 = *(const float4*)(xp + 4);
        af[mi][0] = f2bf(x0.x);
        af[mi][1] = f2bf(x0.y);
        af[mi][2] = f2bf(x0.z);
        af[mi][3] = f2bf(x0.w);
        af[mi][4] = f2bf(x1.x);
        af[mi][5] = f2bf(x1.y);
        af[mi][6] = f2bf(x1.z);
        af[mi][7] = f2bf(x1.w);
      }
    }
    bf16x8 bfr[NF];
#pragma unroll
    for (int nf = 0; nf < NF; ++nf)
      bfr[nf] = ((const bf16x8*)Blds)[(ks * NPF + wn * NF + nf) * 64 + lane];
#pragma unroll
    for (int mi = 0; mi < 4; ++mi)
#pragma unroll
      for (int nf = 0; nf < NF; ++nf)
        acc[mi][nf] = __builtin_amdgcn_mfma_f32_16x16x32_bf16(af[mi], bfr[nf], acc[mi][nf], 0, 0, 0);
  }

#pragma unroll
  for (int mi = 0; mi < 4; ++mi) {
    int r0 = rowbase + mi * 16 + lgrp * 4;
#pragma unroll
    for (int nf = 0; nf < NF; ++nf) {
      int colc = (wn * NF + nf) * 16 + lrow;
#pragma unroll
      for (int rr = 0; rr < 4; ++rr) {
        int r = r0 + rr;
        if (r < n) H[(size_t)r * NTOT + colc] = f2bf(acc[mi][nf][rr]);
      }
    }
  }
}

// ---------------- fused CSR gather (bf16 features in, bf16 or f32 out) ----------------
// out[d] = act( h[d]*dinv[d]^2 + sum_e h[src]*nrm_e + b )

template <int CH, bool RELU, bool OUT_BF16>
__global__ __launch_bounds__(256) void gather_kernel(
    const short* __restrict__ h, const float* __restrict__ dinv, const float* __restrict__ b,
    const int* __restrict__ start, const int2* __restrict__ csr, void* __restrict__ outp,
    int n, int e_cnt) {
  constexpr int TPN = CH / 8;        // threads per node (8 ch each)
  constexpr int NPB = 256 / TPN;     // nodes per block
  const int tid = threadIdx.x;
  const int q = tid % TPN;
  const int g = tid / TPN;
  const int d = blockIdx.x * NPB + g;
  if (d >= n) return;
  const bf16x8* h8 = (const bf16x8*)h;
  float s = dinv[d];
  s = s * s;
  bf16x8 v = h8[(size_t)d * TPN + q];
  float acc[8];
#pragma unroll
  for (int j = 0; j < 8; ++j) acc[j] = bf2f(v[j]) * s;
  const int k0 = start[d];
  const int k1 = (d + 1 < n) ? start[d + 1] : e_cnt;
  for (int k = k0; k < k1; ++k) {
    int2 e = csr[k];
    union { int i; float f; } u;
    u.i = e.y;
    float nv = u.f;
    bf16x8 hv = h8[(size_t)e.x * TPN + q];
#pragma unroll
    for (int j = 0; j < 8; ++j) acc[j] += bf2f(hv[j]) * nv;
  }
#pragma unroll
  for (int j = 0; j < 8; ++j) acc[j] += b[q * 8 + j];
  if (RELU) {
#pragma unroll
    for (int j = 0; j < 8; ++j) acc[j] = fmaxf(acc[j], 0.f);
  }
  if (OUT_BF16) {
    bf16x8 ov;
#pragma unroll
    for (int j = 0; j < 8; ++j) ov[j] = f2bf(acc[j]);
    ((bf16x8*)outp)[(size_t)d * TPN + q] = ov;
  } else {
    float4* op = (float4*)outp + (size_t)d * (CH / 4) + q * 2;
    op[0] = make_float4(acc[0], acc[1], acc[2], acc[3]);
    op[1] = make_float4(acc[4], acc[5], acc[6], acc[7]);
  }
}

// ---------------- launch ----------------

extern "C" void kernel_launch(void* const* d_in, const int* in_sizes, int n_in,
                              void* d_out, int out_size, void* d_ws, size_t ws_size,
                              hipStream_t stream) {
  const float* x = (const float*)d_in[0];
  const int* ei = (const int*)d_in[1];
  const float* ew = (const float*)d_in[2];
  const float* W1 = (const float*)d_in[3];
  const float* b1 = (const float*)d_in[4];
  const float* W2 = (const float*)d_in[5];
  const float* b2 = (const float*)d_in[6];
  float* outp = (float*)d_out;

  const int N = NNODES, E = NEDGES;
  const int* rowp = ei;
  const int* colp = ei + E;
  const int NB = (N + 255) / 256;
  const int EB = (E + 255) / 256;

  // workspace carve-up (deg & cnt adjacent -> single memset)
  char* wsb = (char*)d_ws;
  float* deg = (float*)wsb;     wsb += (size_t)N * 4;
  int* cnt = (int*)wsb;         wsb += (size_t)N * 4;
  float* dinv = (float*)wsb;    wsb += (size_t)N * 4;
  int* start = (int*)wsb;       wsb += (size_t)N * 4;
  int* cursor = (int*)wsb;      wsb += (size_t)N * 4;
  int* bsum = (int*)wsb;        wsb += (size_t)256 * 4;
  int2* csr = (int2*)wsb;       wsb += (size_t)E * 8;
  short* h1 = (short*)wsb;      wsb += (size_t)N * 128 * 2;
  short* h1r = (short*)wsb;     wsb += (size_t)N * 128 * 2;
  short* h2 = (short*)wsb;      wsb += (size_t)N * 64 * 2;

  // norm + CSR build
  hipMemsetAsync(deg, 0, (size_t)N * 2 * 4, stream);  // zeroes deg and cnt
  deg_count_kernel<<<EB, 256, 0, stream>>>(colp, ew, deg, cnt, E);
  scan1_kernel<<<NB, 256, 0, stream>>>(cnt, start, bsum, N);
  scan2_kernel<<<1, 256, 0, stream>>>(bsum, NB);
  scan3_kernel<<<NB, 256, 0, stream>>>(start, bsum, cursor, deg, dinv, N);
  fill_kernel<<<EB, 256, 0, stream>>>(rowp, colp, ew, dinv, cursor, csr, E);

  // layer 1: MFMA GEMM (f32 A) -> bf16 h1; gather (+bias+relu) -> bf16 h1r
  mfma_gemm_kernel<256, 128, false><<<(N + 127) / 128, 256, 0, stream>>>(x, W1, h1, N);
  gather_kernel<128, true, true><<<(N + 15) / 16, 256, 0, stream>>>(h1, dinv, b1, start, csr,
                                                                    h1r, N, E);

  // layer 2: MFMA GEMM (bf16 A) -> bf16 h2; gather (+bias) -> f32 out
  mfma_gemm_kernel<128, 64, true><<<(N + 127) / 128, 256, 0, stream>>>(h1r, W2, h2, N);
  gather_kernel<64, false, false><<<(N + 31) / 32, 256, 0, stream>>>(h2, dinv, b2, start, csr,
                                                                     outp, N, E);
}

// Round 5
// 200.069 us; speedup vs baseline: 12.6707x; 1.1939x over previous
//
#include <hip/hip_runtime.h>
#include <hip/hip_bf16.h>
#include <math.h>

static constexpr int NNODES = 50000;
static constexpr int NEDGES = 800000;

typedef __attribute__((ext_vector_type(8))) short bf16x8;
typedef __attribute__((ext_vector_type(4))) float f32x4;

__device__ inline short f2bf(float f) {
  union { __hip_bfloat16 h; short s; } u;
  u.h = __float2bfloat16(f);
  return u.s;
}

__device__ inline float bf2f(short s) {
  union { unsigned int u; float f; } u;
  u.u = ((unsigned int)(unsigned short)s) << 16;
  return u.f;
}

// ---------------- fused deg + count: ONE u64 atomic per edge ----------------
// bits [0,42):  sum of w in 2^-32 fixed point (w in [0,1), deg <= 1024 -> < 2^42)
// bits [42,64): edge count

static constexpr unsigned long long DEG_MASK = (1ULL << 42) - 1;

__global__ void deg_count_kernel(const int* __restrict__ col, const float* __restrict__ w,
                                 unsigned long long* __restrict__ packed, int e_cnt) {
  int i = blockIdx.x * 256 + threadIdx.x;
  if (i < e_cnt) {
    unsigned long long c =
        (1ULL << 42) + (unsigned long long)((double)w[i] * 4294967296.0);
    atomicAdd(&packed[col[i]], c);
  }
}

// ---------------- scans ----------------

__global__ void scan1_kernel(const unsigned long long* __restrict__ packed,
                             int* __restrict__ excl, int* __restrict__ bsum, int n) {
  __shared__ int buf[256];
  int tid = threadIdx.x;
  int i = blockIdx.x * 256 + tid;
  int v = (i < n) ? (int)(packed[i] >> 42) : 0;
  buf[tid] = v;
  __syncthreads();
  for (int off = 1; off < 256; off <<= 1) {
    int t = (tid >= off) ? buf[tid - off] : 0;
    __syncthreads();
    buf[tid] += t;
    __syncthreads();
  }
  if (i < n) excl[i] = buf[tid] - v;
  if (tid == 255) bsum[blockIdx.x] = buf[255];
}

__global__ void scan2_kernel(int* __restrict__ bsum, int nb) {
  __shared__ int buf[256];
  int tid = threadIdx.x;
  int v = (tid < nb) ? bsum[tid] : 0;
  buf[tid] = v;
  __syncthreads();
  for (int off = 1; off < 256; off <<= 1) {
    int t = (tid >= off) ? buf[tid - off] : 0;
    __syncthreads();
    buf[tid] += t;
    __syncthreads();
  }
  if (tid < nb) bsum[tid] = buf[tid] - v;
}

// add block offsets, copy to cursor, and compute dinv from packed deg (fused)
__global__ void scan3_kernel(int* __restrict__ excl, const int* __restrict__ bsum,
                             int* __restrict__ cursor,
                             const unsigned long long* __restrict__ packed,
                             float* __restrict__ dinv, int n) {
  int i = blockIdx.x * 256 + threadIdx.x;
  if (i < n) {
    int s = excl[i] + bsum[blockIdx.x];
    excl[i] = s;
    cursor[i] = s;
    double d = (double)(packed[i] & DEG_MASK) * (1.0 / 4294967296.0) + 1.0;
    dinv[i] = 1.0f / sqrtf((float)d);
  }
}

// ---------------- fill (norm fused in, packed int2 {src, bits(nrm)}) ----------------

__global__ void fill_kernel(const int* __restrict__ row, const int* __restrict__ col,
                            const float* __restrict__ w, const float* __restrict__ dinv,
                            int* __restrict__ cursor, int2* __restrict__ csr, int e_cnt) {
  int i = blockIdx.x * 256 + threadIdx.x;
  if (i < e_cnt) {
    int r = row[i], d = col[i];
    float nv = dinv[r] * w[i] * dinv[d];
    int p = atomicAdd(&cursor[d], 1);
    int2 e;
    e.x = r;
    union { float f; int i; } u;
    u.f = nv;
    e.y = u.i;
    csr[p] = e;
  }
}

// ---------------- bf16 MFMA GEMM: H[n][NTOT] = A[n][K] @ W[K][NTOT], H in bf16 ----------
// Block: 256 threads = 4 waves (2M x 2N). Block tile = 128 rows x NTOT cols.
// W staged ONCE into LDS (fragment-major bf16). A either f32 (converted) or bf16.
// D layout col=lane&15, row=(lane>>4)*4+reg [m89-verified].

template <int K, int NTOT, bool A_BF16>
__global__ __launch_bounds__(256) void mfma_gemm_kernel(const void* __restrict__ Av,
                                                        const float* __restrict__ W,
                                                        short* __restrict__ H, int n) {
  constexpr int KF = K / 32;
  constexpr int NPF = NTOT / 16;
  constexpr int NF = NTOT / 32;
  __shared__ alignas(16) short Blds[KF * NPF * 64 * 8];
  const int tid = threadIdx.x;
  const int lane = tid & 63;
  const int wave = tid >> 6;
  const int lrow = lane & 15;
  const int lgrp = lane >> 4;

  for (int f = wave; f < KF * NPF; f += 4) {
    int kf = f / NPF, nfb = f % NPF;
    int colc = nfb * 16 + lrow;
    int krow = kf * 32 + lgrp * 8;
    bf16x8 bv;
#pragma unroll
    for (int i = 0; i < 8; ++i) bv[i] = f2bf(W[(size_t)(krow + i) * NTOT + colc]);
    ((bf16x8*)Blds)[f * 64 + lane] = bv;
  }
  __syncthreads();

  const int wm = wave >> 1, wn = wave & 1;
  const int rowbase = blockIdx.x * 128 + wm * 64;
  const int nmax = n - 1;
  f32x4 acc[4][NF] = {};

  for (int ks = 0; ks < KF; ++ks) {
    bf16x8 af[4];
#pragma unroll
    for (int mi = 0; mi < 4; ++mi) {
      int r = rowbase + mi * 16 + lrow;
      r = r > nmax ? nmax : r;
      if (A_BF16) {
        const short* X = (const short*)Av;
        af[mi] = *(const bf16x8*)(X + (size_t)r * K + ks * 32 + lgrp * 8);
      } else {
        const float* X = (const float*)Av;
        const float* xp = X + (size_t)r * K + ks * 32 + lgrp * 8;
        float4 x0 = *(const float4*)xp;
        float4 x1 = *(const float4*)(xp + 4);
        af[mi][0] = f2bf(x0.x);
        af[mi][1] = f2bf(x0.y);
        af[mi][2] = f2bf(x0.z);
        af[mi][3] = f2bf(x0.w);
        af[mi][4] = f2bf(x1.x);
        af[mi][5] = f2bf(x1.y);
        af[mi][6] = f2bf(x1.z);
        af[mi][7] = f2bf(x1.w);
      }
    }
    bf16x8 bfr[NF];
#pragma unroll
    for (int nf = 0; nf < NF; ++nf)
      bfr[nf] = ((const bf16x8*)Blds)[(ks * NPF + wn * NF + nf) * 64 + lane];
#pragma unroll
    for (int mi = 0; mi < 4; ++mi)
#pragma unroll
      for (int nf = 0; nf < NF; ++nf)
        acc[mi][nf] = __builtin_amdgcn_mfma_f32_16x16x32_bf16(af[mi], bfr[nf], acc[mi][nf], 0, 0, 0);
  }

#pragma unroll
  for (int mi = 0; mi < 4; ++mi) {
    int r0 = rowbase + mi * 16 + lgrp * 4;
#pragma unroll
    for (int nf = 0; nf < NF; ++nf) {
      int colc = (wn * NF + nf) * 16 + lrow;
#pragma unroll
      for (int rr = 0; rr < 4; ++rr) {
        int r = r0 + rr;
        if (r < n) H[(size_t)r * NTOT + colc] = f2bf(acc[mi][nf][rr]);
      }
    }
  }
}

// ---------------- fused CSR gather (bf16 features in, bf16 or f32 out) ----------------
// out[d] = act( h[d]*dinv[d]^2 + sum_e h[src]*nrm_e + b )

template <int CH, bool RELU, bool OUT_BF16>
__global__ __launch_bounds__(256) void gather_kernel(
    const short* __restrict__ h, const float* __restrict__ dinv, const float* __restrict__ b,
    const int* __restrict__ start, const int2* __restrict__ csr, void* __restrict__ outp,
    int n, int e_cnt) {
  constexpr int TPN = CH / 8;        // threads per node (8 ch each)
  constexpr int NPB = 256 / TPN;     // nodes per block
  const int tid = threadIdx.x;
  const int q = tid % TPN;
  const int g = tid / TPN;
  const int d = blockIdx.x * NPB + g;
  if (d >= n) return;
  const bf16x8* h8 = (const bf16x8*)h;
  float s = dinv[d];
  s = s * s;
  bf16x8 v = h8[(size_t)d * TPN + q];
  float acc[8];
#pragma unroll
  for (int j = 0; j < 8; ++j) acc[j] = bf2f(v[j]) * s;
  const int k0 = start[d];
  const int k1 = (d + 1 < n) ? start[d + 1] : e_cnt;
  for (int k = k0; k < k1; ++k) {
    int2 e = csr[k];
    union { int i; float f; } u;
    u.i = e.y;
    float nv = u.f;
    bf16x8 hv = h8[(size_t)e.x * TPN + q];
#pragma unroll
    for (int j = 0; j < 8; ++j) acc[j] += bf2f(hv[j]) * nv;
  }
#pragma unroll
  for (int j = 0; j < 8; ++j) acc[j] += b[q * 8 + j];
  if (RELU) {
#pragma unroll
    for (int j = 0; j < 8; ++j) acc[j] = fmaxf(acc[j], 0.f);
  }
  if (OUT_BF16) {
    bf16x8 ov;
#pragma unroll
    for (int j = 0; j < 8; ++j) ov[j] = f2bf(acc[j]);
    ((bf16x8*)outp)[(size_t)d * TPN + q] = ov;
  } else {
    float4* op = (float4*)outp + (size_t)d * (CH / 4) + q * 2;
    op[0] = make_float4(acc[0], acc[1], acc[2], acc[3]);
    op[1] = make_float4(acc[4], acc[5], acc[6], acc[7]);
  }
}

// ---------------- launch ----------------

extern "C" void kernel_launch(void* const* d_in, const int* in_sizes, int n_in,
                              void* d_out, int out_size, void* d_ws, size_t ws_size,
                              hipStream_t stream) {
  const float* x = (const float*)d_in[0];
  const int* ei = (const int*)d_in[1];
  const float* ew = (const float*)d_in[2];
  const float* W1 = (const float*)d_in[3];
  const float* b1 = (const float*)d_in[4];
  const float* W2 = (const float*)d_in[5];
  const float* b2 = (const float*)d_in[6];
  float* outp = (float*)d_out;

  const int N = NNODES, E = NEDGES;
  const int* rowp = ei;
  const int* colp = ei + E;
  const int NB = (N + 255) / 256;
  const int EB = (E + 255) / 256;

  // workspace carve-up
  char* wsb = (char*)d_ws;
  unsigned long long* packed = (unsigned long long*)wsb;  wsb += (size_t)N * 8;
  float* dinv = (float*)wsb;    wsb += (size_t)N * 4;
  int* start = (int*)wsb;       wsb += (size_t)N * 4;
  int* cursor = (int*)wsb;      wsb += (size_t)N * 4;
  int* bsum = (int*)wsb;        wsb += (size_t)256 * 4;
  int2* csr = (int2*)wsb;       wsb += (size_t)E * 8;
  short* h1 = (short*)wsb;      wsb += (size_t)N * 128 * 2;
  short* h1r = (short*)wsb;     wsb += (size_t)N * 128 * 2;
  short* h2 = (short*)wsb;      wsb += (size_t)N * 64 * 2;

  // norm + CSR build
  hipMemsetAsync(packed, 0, (size_t)N * 8, stream);
  deg_count_kernel<<<EB, 256, 0, stream>>>(colp, ew, packed, E);
  scan1_kernel<<<NB, 256, 0, stream>>>(packed, start, bsum, N);
  scan2_kernel<<<1, 256, 0, stream>>>(bsum, NB);
  scan3_kernel<<<NB, 256, 0, stream>>>(start, bsum, cursor, packed, dinv, N);
  fill_kernel<<<EB, 256, 0, stream>>>(rowp, colp, ew, dinv, cursor, csr, E);

  // layer 1: MFMA GEMM (f32 A) -> bf16 h1; gather (+bias+relu) -> bf16 h1r
  mfma_gemm_kernel<256, 128, false><<<(N + 127) / 128, 256, 0, stream>>>(x, W1, h1, N);
  gather_kernel<128, true, true><<<(N + 15) / 16, 256, 0, stream>>>(h1, dinv, b1, start, csr,
                                                                    h1r, N, E);

  // layer 2: MFMA GEMM (bf16 A) -> bf16 h2; gather (+bias) -> f32 out
  mfma_gemm_kernel<128, 64, true><<<(N + 127) / 128, 256, 0, stream>>>(h1r, W2, h2, N);
  gather_kernel<64, false, false><<<(N + 31) / 32, 256, 0, stream>>>(h2, dinv, b2, start, csr,
                                                                     outp, N, E);
}

// Round 6
// 194.319 us; speedup vs baseline: 13.0457x; 1.0296x over previous
//
#include <hip/hip_runtime.h>
#include <hip/hip_bf16.h>
#include <math.h>

static constexpr int NNODES = 50000;
static constexpr int NEDGES = 800000;

typedef __attribute__((ext_vector_type(8))) short bf16x8;
typedef __attribute__((ext_vector_type(4))) float f32x4;

__device__ inline short f2bf(float f) {
  union { __hip_bfloat16 h; short s; } u;
  u.h = __float2bfloat16(f);
  return u.s;
}

__device__ inline float bf2f(short s) {
  union { unsigned int u; float f; } u;
  u.u = ((unsigned int)(unsigned short)s) << 16;
  return u.f;
}

// ---------------- fused deg + count: ONE u64 atomic per edge ----------------
// bits [0,42):  sum of w in 2^-32 fixed point (w in [0,1), deg <= 1024 -> < 2^42)
// bits [42,64): edge count

static constexpr unsigned long long DEG_MASK = (1ULL << 42) - 1;

__global__ void deg_count_kernel(const int* __restrict__ col, const float* __restrict__ w,
                                 unsigned long long* __restrict__ packed, int e_cnt) {
  int i = blockIdx.x * 256 + threadIdx.x;
  if (i < e_cnt) {
    unsigned long long c =
        (1ULL << 42) + (unsigned long long)((double)w[i] * 4294967296.0);
    atomicAdd(&packed[col[i]], c);
  }
}

// ---------------- scans ----------------

__global__ void scan1_kernel(const unsigned long long* __restrict__ packed,
                             int* __restrict__ excl, int* __restrict__ bsum, int n) {
  __shared__ int buf[256];
  int tid = threadIdx.x;
  int i = blockIdx.x * 256 + tid;
  int v = (i < n) ? (int)(packed[i] >> 42) : 0;
  buf[tid] = v;
  __syncthreads();
  for (int off = 1; off < 256; off <<= 1) {
    int t = (tid >= off) ? buf[tid - off] : 0;
    __syncthreads();
    buf[tid] += t;
    __syncthreads();
  }
  if (i < n) excl[i] = buf[tid] - v;
  if (tid == 255) bsum[blockIdx.x] = buf[255];
}

__global__ void scan2_kernel(int* __restrict__ bsum, int nb) {
  __shared__ int buf[256];
  int tid = threadIdx.x;
  int v = (tid < nb) ? bsum[tid] : 0;
  buf[tid] = v;
  __syncthreads();
  for (int off = 1; off < 256; off <<= 1) {
    int t = (tid >= off) ? buf[tid - off] : 0;
    __syncthreads();
    buf[tid] += t;
    __syncthreads();
  }
  if (tid < nb) bsum[tid] = buf[tid] - v;
}

// add block offsets, copy to cursor, and compute dinv from packed deg (fused)
__global__ void scan3_kernel(int* __restrict__ excl, const int* __restrict__ bsum,
                             int* __restrict__ cursor,
                             const unsigned long long* __restrict__ packed,
                             float* __restrict__ dinv, int n) {
  int i = blockIdx.x * 256 + threadIdx.x;
  if (i < n) {
    int s = excl[i] + bsum[blockIdx.x];
    excl[i] = s;
    cursor[i] = s;
    double d = (double)(packed[i] & DEG_MASK) * (1.0 / 4294967296.0) + 1.0;
    dinv[i] = 1.0f / sqrtf((float)d);
  }
}

// ---------------- fill (norm fused in, packed int2 {src, bits(nrm)}) ----------------

__global__ void fill_kernel(const int* __restrict__ row, const int* __restrict__ col,
                            const float* __restrict__ w, const float* __restrict__ dinv,
                            int* __restrict__ cursor, int2* __restrict__ csr, int e_cnt) {
  int i = blockIdx.x * 256 + threadIdx.x;
  if (i < e_cnt) {
    int r = row[i], d = col[i];
    float nv = dinv[r] * w[i] * dinv[d];
    int p = atomicAdd(&cursor[d], 1);
    int2 e;
    e.x = r;
    union { float f; int i; } u;
    u.f = nv;
    e.y = u.i;
    csr[p] = e;
  }
}

// ---------------- bf16 MFMA GEMM: H[n][NTOT] = A[n][K] @ W[K][NTOT], H in bf16 ----------
// Block: 256 threads = 4 waves (2M x 2N). Block tile = 128 rows x NTOT cols.
// W staged ONCE into LDS (fragment-major bf16). A either f32 (converted) or bf16.
// D layout col=lane&15, row=(lane>>4)*4+reg [m89-verified].

template <int K, int NTOT, bool A_BF16>
__global__ __launch_bounds__(256) void mfma_gemm_kernel(const void* __restrict__ Av,
                                                        const float* __restrict__ W,
                                                        short* __restrict__ H, int n) {
  constexpr int KF = K / 32;
  constexpr int NPF = NTOT / 16;
  constexpr int NF = NTOT / 32;
  __shared__ alignas(16) short Blds[KF * NPF * 64 * 8];
  const int tid = threadIdx.x;
  const int lane = tid & 63;
  const int wave = tid >> 6;
  const int lrow = lane & 15;
  const int lgrp = lane >> 4;

  for (int f = wave; f < KF * NPF; f += 4) {
    int kf = f / NPF, nfb = f % NPF;
    int colc = nfb * 16 + lrow;
    int krow = kf * 32 + lgrp * 8;
    bf16x8 bv;
#pragma unroll
    for (int i = 0; i < 8; ++i) bv[i] = f2bf(W[(size_t)(krow + i) * NTOT + colc]);
    ((bf16x8*)Blds)[f * 64 + lane] = bv;
  }
  __syncthreads();

  const int wm = wave >> 1, wn = wave & 1;
  const int rowbase = blockIdx.x * 128 + wm * 64;
  const int nmax = n - 1;
  f32x4 acc[4][NF] = {};

  for (int ks = 0; ks < KF; ++ks) {
    bf16x8 af[4];
#pragma unroll
    for (int mi = 0; mi < 4; ++mi) {
      int r = rowbase + mi * 16 + lrow;
      r = r > nmax ? nmax : r;
      if (A_BF16) {
        const short* X = (const short*)Av;
        af[mi] = *(const bf16x8*)(X + (size_t)r * K + ks * 32 + lgrp * 8);
      } else {
        const float* X = (const float*)Av;
        const float* xp = X + (size_t)r * K + ks * 32 + lgrp * 8;
        float4 x0 = *(const float4*)xp;
        float4 x1 = *(const float4*)(xp + 4);
        af[mi][0] = f2bf(x0.x);
        af[mi][1] = f2bf(x0.y);
        af[mi][2] = f2bf(x0.z);
        af[mi][3] = f2bf(x0.w);
        af[mi][4] = f2bf(x1.x);
        af[mi][5] = f2bf(x1.y);
        af[mi][6] = f2bf(x1.z);
        af[mi][7] = f2bf(x1.w);
      }
    }
    bf16x8 bfr[NF];
#pragma unroll
    for (int nf = 0; nf < NF; ++nf)
      bfr[nf] = ((const bf16x8*)Blds)[(ks * NPF + wn * NF + nf) * 64 + lane];
#pragma unroll
    for (int mi = 0; mi < 4; ++mi)
#pragma unroll
      for (int nf = 0; nf < NF; ++nf)
        acc[mi][nf] = __builtin_amdgcn_mfma_f32_16x16x32_bf16(af[mi], bfr[nf], acc[mi][nf], 0, 0, 0);
  }

#pragma unroll
  for (int mi = 0; mi < 4; ++mi) {
    int r0 = rowbase + mi * 16 + lgrp * 4;
#pragma unroll
    for (int nf = 0; nf < NF; ++nf) {
      int colc = (wn * NF + nf) * 16 + lrow;
#pragma unroll
      for (int rr = 0; rr < 4; ++rr) {
        int r = r0 + rr;
        if (r < n) H[(size_t)r * NTOT + colc] = f2bf(acc[mi][nf][rr]);
      }
    }
  }
}

// ---------------- fused CSR gather (bf16 in, 4-way edge-unrolled MLP) ----------------
// out[d] = act( h[d]*dinv[d]^2 + sum_e h[src]*nrm_e + b )
// 4 independent accumulator sets keep 4 h-row loads in flight per thread.

template <int CH, bool RELU, bool OUT_BF16>
__global__ __launch_bounds__(256) void gather_kernel(
    const short* __restrict__ h, const float* __restrict__ dinv, const float* __restrict__ b,
    const int* __restrict__ start, const int2* __restrict__ csr, void* __restrict__ outp,
    int n, int e_cnt) {
  constexpr int TPN = CH / 8;        // threads per node (8 ch each)
  constexpr int NPB = 256 / TPN;     // nodes per block
  const int tid = threadIdx.x;
  const int q = tid % TPN;
  const int g = tid / TPN;
  const int d = blockIdx.x * NPB + g;
  if (d >= n) return;
  const bf16x8* h8 = (const bf16x8*)h;
  float s = dinv[d];
  s = s * s;
  bf16x8 v = h8[(size_t)d * TPN + q];
  float a0[8], a1[8], a2[8], a3[8];
#pragma unroll
  for (int j = 0; j < 8; ++j) {
    a0[j] = bf2f(v[j]) * s + b[q * 8 + j];
    a1[j] = 0.f;
    a2[j] = 0.f;
    a3[j] = 0.f;
  }
  const int k0 = start[d];
  const int k1 = (d + 1 < n) ? start[d + 1] : e_cnt;
  int k = k0;
  for (; k + 4 <= k1; k += 4) {
    int2 e0 = csr[k];
    int2 e1 = csr[k + 1];
    int2 e2 = csr[k + 2];
    int2 e3 = csr[k + 3];
    bf16x8 h0 = h8[(size_t)e0.x * TPN + q];
    bf16x8 h1 = h8[(size_t)e1.x * TPN + q];
    bf16x8 h2 = h8[(size_t)e2.x * TPN + q];
    bf16x8 h3 = h8[(size_t)e3.x * TPN + q];
    float n0 = __int_as_float(e0.y);
    float n1 = __int_as_float(e1.y);
    float n2 = __int_as_float(e2.y);
    float n3 = __int_as_float(e3.y);
#pragma unroll
    for (int j = 0; j < 8; ++j) {
      a0[j] += bf2f(h0[j]) * n0;
      a1[j] += bf2f(h1[j]) * n1;
      a2[j] += bf2f(h2[j]) * n2;
      a3[j] += bf2f(h3[j]) * n3;
    }
  }
  for (; k < k1; ++k) {
    int2 e = csr[k];
    float nv = __int_as_float(e.y);
    bf16x8 hv = h8[(size_t)e.x * TPN + q];
#pragma unroll
    for (int j = 0; j < 8; ++j) a0[j] += bf2f(hv[j]) * nv;
  }
#pragma unroll
  for (int j = 0; j < 8; ++j) a0[j] += (a1[j] + a2[j]) + a3[j];
  if (RELU) {
#pragma unroll
    for (int j = 0; j < 8; ++j) a0[j] = fmaxf(a0[j], 0.f);
  }
  if (OUT_BF16) {
    bf16x8 ov;
#pragma unroll
    for (int j = 0; j < 8; ++j) ov[j] = f2bf(a0[j]);
    ((bf16x8*)outp)[(size_t)d * TPN + q] = ov;
  } else {
    float4* op = (float4*)outp + (size_t)d * (CH / 4) + q * 2;
    op[0] = make_float4(a0[0], a0[1], a0[2], a0[3]);
    op[1] = make_float4(a0[4], a0[5], a0[6], a0[7]);
  }
}

// ---------------- launch ----------------

extern "C" void kernel_launch(void* const* d_in, const int* in_sizes, int n_in,
                              void* d_out, int out_size, void* d_ws, size_t ws_size,
                              hipStream_t stream) {
  const float* x = (const float*)d_in[0];
  const int* ei = (const int*)d_in[1];
  const float* ew = (const float*)d_in[2];
  const float* W1 = (const float*)d_in[3];
  const float* b1 = (const float*)d_in[4];
  const float* W2 = (const float*)d_in[5];
  const float* b2 = (const float*)d_in[6];
  float* outp = (float*)d_out;

  const int N = NNODES, E = NEDGES;
  const int* rowp = ei;
  const int* colp = ei + E;
  const int NB = (N + 255) / 256;
  const int EB = (E + 255) / 256;

  // workspace carve-up
  char* wsb = (char*)d_ws;
  unsigned long long* packed = (unsigned long long*)wsb;  wsb += (size_t)N * 8;
  float* dinv = (float*)wsb;    wsb += (size_t)N * 4;
  int* start = (int*)wsb;       wsb += (size_t)N * 4;
  int* cursor = (int*)wsb;      wsb += (size_t)N * 4;
  int* bsum = (int*)wsb;        wsb += (size_t)256 * 4;
  int2* csr = (int2*)wsb;       wsb += (size_t)E * 8;
  short* h1 = (short*)wsb;      wsb += (size_t)N * 128 * 2;
  short* h1r = (short*)wsb;     wsb += (size_t)N * 128 * 2;
  short* h2 = (short*)wsb;      wsb += (size_t)N * 64 * 2;

  // norm + CSR build
  hipMemsetAsync(packed, 0, (size_t)N * 8, stream);
  deg_count_kernel<<<EB, 256, 0, stream>>>(colp, ew, packed, E);
  scan1_kernel<<<NB, 256, 0, stream>>>(packed, start, bsum, N);
  scan2_kernel<<<1, 256, 0, stream>>>(bsum, NB);
  scan3_kernel<<<NB, 256, 0, stream>>>(start, bsum, cursor, packed, dinv, N);
  fill_kernel<<<EB, 256, 0, stream>>>(rowp, colp, ew, dinv, cursor, csr, E);

  // layer 1: MFMA GEMM (f32 A) -> bf16 h1; gather (+bias+relu) -> bf16 h1r
  mfma_gemm_kernel<256, 128, false><<<(N + 127) / 128, 256, 0, stream>>>(x, W1, h1, N);
  gather_kernel<128, true, true><<<(N + 15) / 16, 256, 0, stream>>>(h1, dinv, b1, start, csr,
                                                                    h1r, N, E);

  // layer 2: MFMA GEMM (bf16 A) -> bf16 h2; gather (+bias) -> f32 out
  mfma_gemm_kernel<128, 64, true><<<(N + 127) / 128, 256, 0, stream>>>(h1r, W2, h2, N);
  gather_kernel<64, false, false><<<(N + 31) / 32, 256, 0, stream>>>(h2, dinv, b2, start, csr,
                                                                     outp, N, E);
}

// Round 7
// 130.200 us; speedup vs baseline: 19.4702x; 1.4925x over previous
//
#include <hip/hip_runtime.h>
#include <hip/hip_bf16.h>
#include <math.h>

static constexpr int NNODES = 50000;
static constexpr int NEDGES = 800000;
static constexpr int NBUCK = (NNODES + 255) >> 8;  // 196 buckets of 256 dst nodes
static constexpr int MAXB = 6144;  // max edges/bucket (mean 4096, sigma 64 -> +32 sigma)

typedef __attribute__((ext_vector_type(8))) short bf16x8;
typedef __attribute__((ext_vector_type(4))) float f32x4;

__device__ inline short f2bf(float f) {
  union { __hip_bfloat16 h; short s; } u;
  u.h = __float2bfloat16(f);
  return u.s;
}

__device__ inline float bf2f(short s) {
  union { unsigned int u; float f; } u;
  u.u = ((unsigned int)(unsigned short)s) << 16;
  return u.f;
}

// ---------------- bucketed CSR build ----------------

__global__ void initcur_kernel(int* __restrict__ gcur) {
  int b = threadIdx.x;
  if (b < NBUCK) gcur[b] = b * MAXB;
}

// bin 2048 edges/WG into per-bucket regions. Per-WG LDS histogram -> ONE global
// atomic per (WG, bucket) -> contiguous run reservation -> direct int4 writes.
__global__ __launch_bounds__(256) void bin_kernel(const int* __restrict__ row,
                                                  const int* __restrict__ col,
                                                  const float* __restrict__ w,
                                                  int* __restrict__ gcur,
                                                  int4* __restrict__ binned, int e_cnt) {
  __shared__ int rcnt[NBUCK];
  __shared__ int rcur[NBUCK];
  __shared__ int gbase[NBUCK];
  const int tid = threadIdx.x;
  for (int b = tid; b < NBUCK; b += 256) {
    rcnt[b] = 0;
    rcur[b] = 0;
  }
  __syncthreads();
  const int base = blockIdx.x * 2048;
  int srcs[8], dsts[8];
  float ws_[8];
#pragma unroll
  for (int j = 0; j < 8; ++j) {
    int idx = base + tid + 256 * j;
    if (idx < e_cnt) {
      srcs[j] = row[idx];
      dsts[j] = col[idx];
      ws_[j] = w[idx];
      atomicAdd(&rcnt[dsts[j] >> 8], 1);
    } else {
      dsts[j] = -1;
    }
  }
  __syncthreads();
  for (int b = tid; b < NBUCK; b += 256)
    if (rcnt[b] > 0) gbase[b] = atomicAdd(&gcur[b], rcnt[b]);
  __syncthreads();
#pragma unroll
  for (int j = 0; j < 8; ++j) {
    if (dsts[j] >= 0) {
      int b = dsts[j] >> 8;
      int pos = gbase[b] + atomicAdd(&rcur[b], 1);
      binned[pos] = make_int4(srcs[j], dsts[j], __float_as_int(ws_[j]), 0);
    }
  }
}

// per-bucket deg (LDS f32 atomics) + cnt; coalesced dinv/cntg writes
__global__ __launch_bounds__(256) void bdeg_kernel(const int4* __restrict__ binned,
                                                   const int* __restrict__ gcur,
                                                   float* __restrict__ dinv,
                                                   int* __restrict__ cntg, int n) {
  __shared__ float degf[256];
  __shared__ int cnt[256];
  const int b = blockIdx.x, tid = threadIdx.x;
  degf[tid] = 0.f;
  cnt[tid] = 0;
  __syncthreads();
  const int bcnt = gcur[b] - b * MAXB;
  const int4* bp = binned + (size_t)b * MAXB;
  for (int i = tid; i < bcnt; i += 256) {
    int4 e = bp[i];
    int dl = e.y & 255;
    atomicAdd(&degf[dl], __int_as_float(e.z));
    atomicAdd(&cnt[dl], 1);
  }
  __syncthreads();
  int node = b * 256 + tid;
  if (node < n) {
    dinv[node] = 1.0f / sqrtf(degf[tid] + 1.0f);  // self-loop weight 1.0
    cntg[node] = cnt[tid];
  }
}

// exclusive scan of the 196 bucket counts (single WG)
__global__ void bscan_kernel(const int* __restrict__ gcur, int* __restrict__ bbase) {
  __shared__ int buf[256];
  int tid = threadIdx.x;
  int v = (tid < NBUCK) ? gcur[tid] - tid * MAXB : 0;
  buf[tid] = v;
  __syncthreads();
  for (int off = 1; off < 256; off <<= 1) {
    int t = (tid >= off) ? buf[tid - off] : 0;
    __syncthreads();
    buf[tid] += t;
    __syncthreads();
  }
  if (tid < NBUCK) bbase[tid] = buf[tid] - v;
}

// per-bucket: local scan -> start[]; norm + CSR fill via LDS cursors.
// Bucket's csr segment written by ONE workgroup -> line-granular writeback.
__global__ __launch_bounds__(256) void csrfill_kernel(
    const int4* __restrict__ binned, const int* __restrict__ gcur,
    const int* __restrict__ bbase, const float* __restrict__ dinv,
    const int* __restrict__ cntg, int* __restrict__ start, int2* __restrict__ csr, int n) {
  __shared__ float dvL[256];
  __shared__ int cur[256];
  __shared__ int buf[256];
  const int b = blockIdx.x, tid = threadIdx.x;
  const int node = b * 256 + tid;
  int c = (node < n) ? cntg[node] : 0;
  dvL[tid] = (node < n) ? dinv[node] : 0.f;
  buf[tid] = c;
  __syncthreads();
  for (int off = 1; off < 256; off <<= 1) {
    int t = (tid >= off) ? buf[tid - off] : 0;
    __syncthreads();
    buf[tid] += t;
    __syncthreads();
  }
  int localstart = buf[tid] - c;
  const int gb = bbase[b];
  if (node < n) start[node] = gb + localstart;
  cur[tid] = localstart;
  __syncthreads();
  const int bcnt = gcur[b] - b * MAXB;
  const int4* bp = binned + (size_t)b * MAXB;
  for (int i = tid; i < bcnt; i += 256) {
    int4 e = bp[i];
    int dl = e.y & 255;
    float nrm = dinv[e.x] * __int_as_float(e.z) * dvL[dl];
    int pos = gb + atomicAdd(&cur[dl], 1);
    csr[pos] = make_int2(e.x, __float_as_int(nrm));
  }
}

// ---------------- bf16 MFMA GEMM: H[n][NTOT] = A[n][K] @ W[K][NTOT], H in bf16 ----------
// Block: 256 threads = 4 waves (2M x 2N). Block tile = 128 rows x NTOT cols.
// W staged ONCE into LDS (fragment-major bf16). A either f32 (converted) or bf16.
// D layout col=lane&15, row=(lane>>4)*4+reg [m89-verified].

template <int K, int NTOT, bool A_BF16>
__global__ __launch_bounds__(256) void mfma_gemm_kernel(const void* __restrict__ Av,
                                                        const float* __restrict__ W,
                                                        short* __restrict__ H, int n) {
  constexpr int KF = K / 32;
  constexpr int NPF = NTOT / 16;
  constexpr int NF = NTOT / 32;
  __shared__ alignas(16) short Blds[KF * NPF * 64 * 8];
  const int tid = threadIdx.x;
  const int lane = tid & 63;
  const int wave = tid >> 6;
  const int lrow = lane & 15;
  const int lgrp = lane >> 4;

  for (int f = wave; f < KF * NPF; f += 4) {
    int kf = f / NPF, nfb = f % NPF;
    int colc = nfb * 16 + lrow;
    int krow = kf * 32 + lgrp * 8;
    bf16x8 bv;
#pragma unroll
    for (int i = 0; i < 8; ++i) bv[i] = f2bf(W[(size_t)(krow + i) * NTOT + colc]);
    ((bf16x8*)Blds)[f * 64 + lane] = bv;
  }
  __syncthreads();

  const int wm = wave >> 1, wn = wave & 1;
  const int rowbase = blockIdx.x * 128 + wm * 64;
  const int nmax = n - 1;
  f32x4 acc[4][NF] = {};

  for (int ks = 0; ks < KF; ++ks) {
    bf16x8 af[4];
#pragma unroll
    for (int mi = 0; mi < 4; ++mi) {
      int r = rowbase + mi * 16 + lrow;
      r = r > nmax ? nmax : r;
      if (A_BF16) {
        const short* X = (const short*)Av;
        af[mi] = *(const bf16x8*)(X + (size_t)r * K + ks * 32 + lgrp * 8);
      } else {
        const float* X = (const float*)Av;
        const float* xp = X + (size_t)r * K + ks * 32 + lgrp * 8;
        float4 x0 = *(const float4*)xp;
        float4 x1 = *(const float4*)(xp + 4);
        af[mi][0] = f2bf(x0.x);
        af[mi][1] = f2bf(x0.y);
        af[mi][2] = f2bf(x0.z);
        af[mi][3] = f2bf(x0.w);
        af[mi][4] = f2bf(x1.x);
        af[mi][5] = f2bf(x1.y);
        af[mi][6] = f2bf(x1.z);
        af[mi][7] = f2bf(x1.w);
      }
    }
    bf16x8 bfr[NF];
#pragma unroll
    for (int nf = 0; nf < NF; ++nf)
      bfr[nf] = ((const bf16x8*)Blds)[(ks * NPF + wn * NF + nf) * 64 + lane];
#pragma unroll
    for (int mi = 0; mi < 4; ++mi)
#pragma unroll
      for (int nf = 0; nf < NF; ++nf)
        acc[mi][nf] = __builtin_amdgcn_mfma_f32_16x16x32_bf16(af[mi], bfr[nf], acc[mi][nf], 0, 0, 0);
  }

#pragma unroll
  for (int mi = 0; mi < 4; ++mi) {
    int r0 = rowbase + mi * 16 + lgrp * 4;
#pragma unroll
    for (int nf = 0; nf < NF; ++nf) {
      int colc = (wn * NF + nf) * 16 + lrow;
#pragma unroll
      for (int rr = 0; rr < 4; ++rr) {
        int r = r0 + rr;
        if (r < n) H[(size_t)r * NTOT + colc] = f2bf(acc[mi][nf][rr]);
      }
    }
  }
}

// ---------------- fused CSR gather (bf16 in, 4-way edge-unrolled MLP) ----------------
// out[d] = act( h[d]*dinv[d]^2 + sum_e h[src]*nrm_e + b )

template <int CH, bool RELU, bool OUT_BF16>
__global__ __launch_bounds__(256) void gather_kernel(
    const short* __restrict__ h, const float* __restrict__ dinv, const float* __restrict__ b,
    const int* __restrict__ start, const int2* __restrict__ csr, void* __restrict__ outp,
    int n, int e_cnt) {
  constexpr int TPN = CH / 8;        // threads per node (8 ch each)
  constexpr int NPB = 256 / TPN;     // nodes per block
  const int tid = threadIdx.x;
  const int q = tid % TPN;
  const int g = tid / TPN;
  const int d = blockIdx.x * NPB + g;
  if (d >= n) return;
  const bf16x8* h8 = (const bf16x8*)h;
  float s = dinv[d];
  s = s * s;
  bf16x8 v = h8[(size_t)d * TPN + q];
  float a0[8], a1[8], a2[8], a3[8];
#pragma unroll
  for (int j = 0; j < 8; ++j) {
    a0[j] = bf2f(v[j]) * s + b[q * 8 + j];
    a1[j] = 0.f;
    a2[j] = 0.f;
    a3[j] = 0.f;
  }
  const int k0 = start[d];
  const int k1 = (d + 1 < n) ? start[d + 1] : e_cnt;
  int k = k0;
  for (; k + 4 <= k1; k += 4) {
    int2 e0 = csr[k];
    int2 e1 = csr[k + 1];
    int2 e2 = csr[k + 2];
    int2 e3 = csr[k + 3];
    bf16x8 h0 = h8[(size_t)e0.x * TPN + q];
    bf16x8 h1 = h8[(size_t)e1.x * TPN + q];
    bf16x8 h2 = h8[(size_t)e2.x * TPN + q];
    bf16x8 h3 = h8[(size_t)e3.x * TPN + q];
    float n0 = __int_as_float(e0.y);
    float n1 = __int_as_float(e1.y);
    float n2 = __int_as_float(e2.y);
    float n3 = __int_as_float(e3.y);
#pragma unroll
    for (int j = 0; j < 8; ++j) {
      a0[j] += bf2f(h0[j]) * n0;
      a1[j] += bf2f(h1[j]) * n1;
      a2[j] += bf2f(h2[j]) * n2;
      a3[j] += bf2f(h3[j]) * n3;
    }
  }
  for (; k < k1; ++k) {
    int2 e = csr[k];
    float nv = __int_as_float(e.y);
    bf16x8 hv = h8[(size_t)e.x * TPN + q];
#pragma unroll
    for (int j = 0; j < 8; ++j) a0[j] += bf2f(hv[j]) * nv;
  }
#pragma unroll
  for (int j = 0; j < 8; ++j) a0[j] += (a1[j] + a2[j]) + a3[j];
  if (RELU) {
#pragma unroll
    for (int j = 0; j < 8; ++j) a0[j] = fmaxf(a0[j], 0.f);
  }
  if (OUT_BF16) {
    bf16x8 ov;
#pragma unroll
    for (int j = 0; j < 8; ++j) ov[j] = f2bf(a0[j]);
    ((bf16x8*)outp)[(size_t)d * TPN + q] = ov;
  } else {
    float4* op = (float4*)outp + (size_t)d * (CH / 4) + q * 2;
    op[0] = make_float4(a0[0], a0[1], a0[2], a0[3]);
    op[1] = make_float4(a0[4], a0[5], a0[6], a0[7]);
  }
}

// ---------------- launch ----------------

extern "C" void kernel_launch(void* const* d_in, const int* in_sizes, int n_in,
                              void* d_out, int out_size, void* d_ws, size_t ws_size,
                              hipStream_t stream) {
  const float* x = (const float*)d_in[0];
  const int* ei = (const int*)d_in[1];
  const float* ew = (const float*)d_in[2];
  const float* W1 = (const float*)d_in[3];
  const float* b1 = (const float*)d_in[4];
  const float* W2 = (const float*)d_in[5];
  const float* b2 = (const float*)d_in[6];
  float* outp = (float*)d_out;

  const int N = NNODES, E = NEDGES;
  const int* rowp = ei;
  const int* colp = ei + E;

  // workspace carve-up (binned first: 16B alignment)
  char* wsb = (char*)d_ws;
  int4* binned = (int4*)wsb;    wsb += (size_t)NBUCK * MAXB * 16;  // 19.3 MB
  int2* csr = (int2*)wsb;       wsb += (size_t)E * 8;              // 6.4 MB
  short* h1 = (short*)wsb;      wsb += (size_t)N * 128 * 2;
  short* h1r = (short*)wsb;     wsb += (size_t)N * 128 * 2;
  short* h2 = (short*)wsb;      wsb += (size_t)N * 64 * 2;
  float* dinv = (float*)wsb;    wsb += (size_t)N * 4;
  int* start = (int*)wsb;       wsb += (size_t)N * 4;
  int* cntg = (int*)wsb;        wsb += (size_t)N * 4;
  int* gcur = (int*)wsb;        wsb += (size_t)NBUCK * 4;
  int* bbase = (int*)wsb;       wsb += (size_t)NBUCK * 4;

  // CSR build: bucketed counting sort (no per-edge global atomics)
  initcur_kernel<<<1, 256, 0, stream>>>(gcur);
  bin_kernel<<<(E + 2047) / 2048, 256, 0, stream>>>(rowp, colp, ew, gcur, binned, E);
  bdeg_kernel<<<NBUCK, 256, 0, stream>>>(binned, gcur, dinv, cntg, N);
  bscan_kernel<<<1, 256, 0, stream>>>(gcur, bbase);
  csrfill_kernel<<<NBUCK, 256, 0, stream>>>(binned, gcur, bbase, dinv, cntg, start, csr, N);

  // layer 1: MFMA GEMM (f32 A) -> bf16 h1; gather (+bias+relu) -> bf16 h1r
  mfma_gemm_kernel<256, 128, false><<<(N + 127) / 128, 256, 0, stream>>>(x, W1, h1, N);
  gather_kernel<128, true, true><<<(N + 15) / 16, 256, 0, stream>>>(h1, dinv, b1, start, csr,
                                                                    h1r, N, E);

  // layer 2: MFMA GEMM (bf16 A) -> bf16 h2; gather (+bias) -> f32 out
  mfma_gemm_kernel<128, 64, true><<<(N + 127) / 128, 256, 0, stream>>>(h1r, W2, h2, N);
  gather_kernel<64, false, false><<<(N + 31) / 32, 256, 0, stream>>>(h2, dinv, b2, start, csr,
                                                                     outp, N, E);
}

// Round 8
// 128.317 us; speedup vs baseline: 19.7559x; 1.0147x over previous
//
#include <hip/hip_runtime.h>
#include <hip/hip_bf16.h>
#include <math.h>

static constexpr int NNODES = 50000;
static constexpr int NEDGES = 800000;
static constexpr int NBUCK = (NNODES + 255) >> 8;  // 196 buckets of 256 dst nodes
static constexpr int MAXB = 6144;  // max edges/bucket (mean 4096, sigma 64 -> +32 sigma)

typedef __attribute__((ext_vector_type(8))) short bf16x8;
typedef __attribute__((ext_vector_type(4))) float f32x4;

__device__ inline short f2bf(float f) {
  union { __hip_bfloat16 h; short s; } u;
  u.h = __float2bfloat16(f);
  return u.s;
}

__device__ inline float bf2f(short s) {
  union { unsigned int u; float f; } u;
  u.u = ((unsigned int)(unsigned short)s) << 16;
  return u.f;
}

// ---------------- bucketed CSR build ----------------

__global__ void initcur_kernel(int* __restrict__ gcur) {
  int b = threadIdx.x;
  if (b < NBUCK) gcur[b] = b * MAXB;
}

// bin 2048 edges/WG into per-bucket regions. Per-WG LDS histogram -> ONE global
// atomic per (WG, bucket) -> contiguous run reservation -> direct int4 writes.
__global__ __launch_bounds__(256) void bin_kernel(const int* __restrict__ row,
                                                  const int* __restrict__ col,
                                                  const float* __restrict__ w,
                                                  int* __restrict__ gcur,
                                                  int4* __restrict__ binned, int e_cnt) {
  __shared__ int rcnt[NBUCK];
  __shared__ int rcur[NBUCK];
  __shared__ int gbase[NBUCK];
  const int tid = threadIdx.x;
  for (int b = tid; b < NBUCK; b += 256) {
    rcnt[b] = 0;
    rcur[b] = 0;
  }
  __syncthreads();
  const int base = blockIdx.x * 2048;
  int srcs[8], dsts[8];
  float ws_[8];
#pragma unroll
  for (int j = 0; j < 8; ++j) {
    int idx = base + tid + 256 * j;
    if (idx < e_cnt) {
      srcs[j] = row[idx];
      dsts[j] = col[idx];
      ws_[j] = w[idx];
      atomicAdd(&rcnt[dsts[j] >> 8], 1);
    } else {
      dsts[j] = -1;
    }
  }
  __syncthreads();
  for (int b = tid; b < NBUCK; b += 256)
    if (rcnt[b] > 0) gbase[b] = atomicAdd(&gcur[b], rcnt[b]);
  __syncthreads();
#pragma unroll
  for (int j = 0; j < 8; ++j) {
    if (dsts[j] >= 0) {
      int b = dsts[j] >> 8;
      int pos = gbase[b] + atomicAdd(&rcur[b], 1);
      binned[pos] = make_int4(srcs[j], dsts[j], __float_as_int(ws_[j]), 0);
    }
  }
}

// per-bucket deg (LDS f32 atomics) + cnt; coalesced dinv/cntg writes
__global__ __launch_bounds__(256) void bdeg_kernel(const int4* __restrict__ binned,
                                                   const int* __restrict__ gcur,
                                                   float* __restrict__ dinv,
                                                   int* __restrict__ cntg, int n) {
  __shared__ float degf[256];
  __shared__ int cnt[256];
  const int b = blockIdx.x, tid = threadIdx.x;
  degf[tid] = 0.f;
  cnt[tid] = 0;
  __syncthreads();
  const int bcnt = gcur[b] - b * MAXB;
  const int4* bp = binned + (size_t)b * MAXB;
  for (int i = tid; i < bcnt; i += 256) {
    int4 e = bp[i];
    int dl = e.y & 255;
    atomicAdd(&degf[dl], __int_as_float(e.z));
    atomicAdd(&cnt[dl], 1);
  }
  __syncthreads();
  int node = b * 256 + tid;
  if (node < n) {
    dinv[node] = 1.0f / sqrtf(degf[tid] + 1.0f);  // self-loop weight 1.0
    cntg[node] = cnt[tid];
  }
}

// exclusive scan of the 196 bucket counts (single WG)
__global__ void bscan_kernel(const int* __restrict__ gcur, int* __restrict__ bbase) {
  __shared__ int buf[256];
  int tid = threadIdx.x;
  int v = (tid < NBUCK) ? gcur[tid] - tid * MAXB : 0;
  buf[tid] = v;
  __syncthreads();
  for (int off = 1; off < 256; off <<= 1) {
    int t = (tid >= off) ? buf[tid - off] : 0;
    __syncthreads();
    buf[tid] += t;
    __syncthreads();
  }
  if (tid < NBUCK) bbase[tid] = buf[tid] - v;
}

// per-bucket: local scan -> start[]; norm + CSR fill via LDS cursors.
__global__ __launch_bounds__(256) void csrfill_kernel(
    const int4* __restrict__ binned, const int* __restrict__ gcur,
    const int* __restrict__ bbase, const float* __restrict__ dinv,
    const int* __restrict__ cntg, int* __restrict__ start, int2* __restrict__ csr, int n) {
  __shared__ float dvL[256];
  __shared__ int cur[256];
  __shared__ int buf[256];
  const int b = blockIdx.x, tid = threadIdx.x;
  const int node = b * 256 + tid;
  int c = (node < n) ? cntg[node] : 0;
  dvL[tid] = (node < n) ? dinv[node] : 0.f;
  buf[tid] = c;
  __syncthreads();
  for (int off = 1; off < 256; off <<= 1) {
    int t = (tid >= off) ? buf[tid - off] : 0;
    __syncthreads();
    buf[tid] += t;
    __syncthreads();
  }
  int localstart = buf[tid] - c;
  const int gb = bbase[b];
  if (node < n) start[node] = gb + localstart;
  cur[tid] = localstart;
  __syncthreads();
  const int bcnt = gcur[b] - b * MAXB;
  const int4* bp = binned + (size_t)b * MAXB;
  for (int i = tid; i < bcnt; i += 256) {
    int4 e = bp[i];
    int dl = e.y & 255;
    float nrm = dinv[e.x] * __int_as_float(e.z) * dvL[dl];
    int pos = gb + atomicAdd(&cur[dl], 1);
    csr[pos] = make_int2(e.x, __float_as_int(nrm));
  }
}

// ---------------- W pre-pack: fragment-major bf16 (one-time, tiny) ----------------
// Fragment f = kf*NPF + nfb; lane l holds W[kf*32 + (l>>4)*8 + i][nfb*16 + (l&15)], i=0..7.

template <int K, int NTOT>
__global__ void packW_kernel(const float* __restrict__ W, short* __restrict__ Wpk) {
  constexpr int KF = K / 32;
  constexpr int NPF = NTOT / 16;
  int t = blockIdx.x * 256 + threadIdx.x;
  if (t >= KF * NPF * 64) return;
  int f = t >> 6, l = t & 63;
  int kf = f / NPF, nfb = f % NPF;
  int col = nfb * 16 + (l & 15);
  int krow = kf * 32 + (l >> 4) * 8;
  bf16x8 bv;
#pragma unroll
  for (int i = 0; i < 8; ++i) bv[i] = f2bf(W[(size_t)(krow + i) * NTOT + col]);
  ((bf16x8*)Wpk)[t] = bv;
}

// ---------------- bf16 MFMA GEMM (no LDS): H = A @ W, W pre-packed ----------------
// Block: 256 threads = 4 waves (2M x 2N). Block tile = 128 rows x NTOT cols.
// B fragments read directly from packed global (L2-hot, 1KB/wave coalesced).
// D layout col=lane&15, row=(lane>>4)*4+reg [m89-verified].

template <int K, int NTOT, bool A_BF16>
__global__ __launch_bounds__(256) void mfma_gemm_kernel(const void* __restrict__ Av,
                                                        const short* __restrict__ Wpk,
                                                        short* __restrict__ H, int n) {
  constexpr int KF = K / 32;
  constexpr int NPF = NTOT / 16;
  constexpr int NF = NTOT / 32;
  const int tid = threadIdx.x;
  const int lane = tid & 63;
  const int wave = tid >> 6;
  const int lrow = lane & 15;
  const int lgrp = lane >> 4;

  const int wm = wave >> 1, wn = wave & 1;
  const int rowbase = blockIdx.x * 128 + wm * 64;
  const int nmax = n - 1;
  const bf16x8* Wf = (const bf16x8*)Wpk;
  f32x4 acc[4][NF] = {};

  for (int ks = 0; ks < KF; ++ks) {
    bf16x8 af[4];
#pragma unroll
    for (int mi = 0; mi < 4; ++mi) {
      int r = rowbase + mi * 16 + lrow;
      r = r > nmax ? nmax : r;
      if (A_BF16) {
        const short* X = (const short*)Av;
        af[mi] = *(const bf16x8*)(X + (size_t)r * K + ks * 32 + lgrp * 8);
      } else {
        const float* X = (const float*)Av;
        const float* xp = X + (size_t)r * K + ks * 32 + lgrp * 8;
        float4 x0 = *(const float4*)xp;
        float4 x1 = *(const float4*)(xp + 4);
        af[mi][0] = f2bf(x0.x);
        af[mi][1] = f2bf(x0.y);
        af[mi][2] = f2bf(x0.z);
        af[mi][3] = f2bf(x0.w);
        af[mi][4] = f2bf(x1.x);
        af[mi][5] = f2bf(x1.y);
        af[mi][6] = f2bf(x1.z);
        af[mi][7] = f2bf(x1.w);
      }
    }
    bf16x8 bfr[NF];
#pragma unroll
    for (int nf = 0; nf < NF; ++nf)
      bfr[nf] = Wf[(ks * NPF + wn * NF + nf) * 64 + lane];
#pragma unroll
    for (int mi = 0; mi < 4; ++mi)
#pragma unroll
      for (int nf = 0; nf < NF; ++nf)
        acc[mi][nf] = __builtin_amdgcn_mfma_f32_16x16x32_bf16(af[mi], bfr[nf], acc[mi][nf], 0, 0, 0);
  }

#pragma unroll
  for (int mi = 0; mi < 4; ++mi) {
    int r0 = rowbase + mi * 16 + lgrp * 4;
#pragma unroll
    for (int nf = 0; nf < NF; ++nf) {
      int colc = (wn * NF + nf) * 16 + lrow;
#pragma unroll
      for (int rr = 0; rr < 4; ++rr) {
        int r = r0 + rr;
        if (r < n) H[(size_t)r * NTOT + colc] = f2bf(acc[mi][nf][rr]);
      }
    }
  }
}

// ---------------- fused CSR gather (bf16 in, 4-way edge-unrolled MLP) ----------------
// out[d] = act( h[d]*dinv[d]^2 + sum_e h[src]*nrm_e + b )

template <int CH, bool RELU, bool OUT_BF16>
__global__ __launch_bounds__(256) void gather_kernel(
    const short* __restrict__ h, const float* __restrict__ dinv, const float* __restrict__ b,
    const int* __restrict__ start, const int2* __restrict__ csr, void* __restrict__ outp,
    int n, int e_cnt) {
  constexpr int TPN = CH / 8;        // threads per node (8 ch each)
  constexpr int NPB = 256 / TPN;     // nodes per block
  const int tid = threadIdx.x;
  const int q = tid % TPN;
  const int g = tid / TPN;
  const int d = blockIdx.x * NPB + g;
  if (d >= n) return;
  const bf16x8* h8 = (const bf16x8*)h;
  float s = dinv[d];
  s = s * s;
  bf16x8 v = h8[(size_t)d * TPN + q];
  float a0[8], a1[8], a2[8], a3[8];
#pragma unroll
  for (int j = 0; j < 8; ++j) {
    a0[j] = bf2f(v[j]) * s + b[q * 8 + j];
    a1[j] = 0.f;
    a2[j] = 0.f;
    a3[j] = 0.f;
  }
  const int k0 = start[d];
  const int k1 = (d + 1 < n) ? start[d + 1] : e_cnt;
  int k = k0;
  for (; k + 4 <= k1; k += 4) {
    int2 e0 = csr[k];
    int2 e1 = csr[k + 1];
    int2 e2 = csr[k + 2];
    int2 e3 = csr[k + 3];
    bf16x8 h0 = h8[(size_t)e0.x * TPN + q];
    bf16x8 h1 = h8[(size_t)e1.x * TPN + q];
    bf16x8 h2 = h8[(size_t)e2.x * TPN + q];
    bf16x8 h3 = h8[(size_t)e3.x * TPN + q];
    float n0 = __int_as_float(e0.y);
    float n1 = __int_as_float(e1.y);
    float n2 = __int_as_float(e2.y);
    float n3 = __int_as_float(e3.y);
#pragma unroll
    for (int j = 0; j < 8; ++j) {
      a0[j] += bf2f(h0[j]) * n0;
      a1[j] += bf2f(h1[j]) * n1;
      a2[j] += bf2f(h2[j]) * n2;
      a3[j] += bf2f(h3[j]) * n3;
    }
  }
  for (; k < k1; ++k) {
    int2 e = csr[k];
    float nv = __int_as_float(e.y);
    bf16x8 hv = h8[(size_t)e.x * TPN + q];
#pragma unroll
    for (int j = 0; j < 8; ++j) a0[j] += bf2f(hv[j]) * nv;
  }
#pragma unroll
  for (int j = 0; j < 8; ++j) a0[j] += (a1[j] + a2[j]) + a3[j];
  if (RELU) {
#pragma unroll
    for (int j = 0; j < 8; ++j) a0[j] = fmaxf(a0[j], 0.f);
  }
  if (OUT_BF16) {
    bf16x8 ov;
#pragma unroll
    for (int j = 0; j < 8; ++j) ov[j] = f2bf(a0[j]);
    ((bf16x8*)outp)[(size_t)d * TPN + q] = ov;
  } else {
    float4* op = (float4*)outp + (size_t)d * (CH / 4) + q * 2;
    op[0] = make_float4(a0[0], a0[1], a0[2], a0[3]);
    op[1] = make_float4(a0[4], a0[5], a0[6], a0[7]);
  }
}

// ---------------- launch ----------------

extern "C" void kernel_launch(void* const* d_in, const int* in_sizes, int n_in,
                              void* d_out, int out_size, void* d_ws, size_t ws_size,
                              hipStream_t stream) {
  const float* x = (const float*)d_in[0];
  const int* ei = (const int*)d_in[1];
  const float* ew = (const float*)d_in[2];
  const float* W1 = (const float*)d_in[3];
  const float* b1 = (const float*)d_in[4];
  const float* W2 = (const float*)d_in[5];
  const float* b2 = (const float*)d_in[6];
  float* outp = (float*)d_out;

  const int N = NNODES, E = NEDGES;
  const int* rowp = ei;
  const int* colp = ei + E;

  // workspace carve-up (binned first: 16B alignment)
  char* wsb = (char*)d_ws;
  int4* binned = (int4*)wsb;    wsb += (size_t)NBUCK * MAXB * 16;  // 19.3 MB
  int2* csr = (int2*)wsb;       wsb += (size_t)E * 8;              // 6.4 MB
  short* h1 = (short*)wsb;      wsb += (size_t)N * 128 * 2;
  short* h1r = (short*)wsb;     wsb += (size_t)N * 128 * 2;
  short* h2 = (short*)wsb;      wsb += (size_t)N * 64 * 2;
  short* Wpk1 = (short*)wsb;    wsb += (size_t)256 * 128 * 2;      // 64 KB packed W1
  short* Wpk2 = (short*)wsb;    wsb += (size_t)128 * 64 * 2;       // 16 KB packed W2
  float* dinv = (float*)wsb;    wsb += (size_t)N * 4;
  int* start = (int*)wsb;       wsb += (size_t)N * 4;
  int* cntg = (int*)wsb;        wsb += (size_t)N * 4;
  int* gcur = (int*)wsb;        wsb += (size_t)NBUCK * 4;
  int* bbase = (int*)wsb;       wsb += (size_t)NBUCK * 4;

  // W pre-pack (tiny, independent of CSR build)
  packW_kernel<256, 128><<<16, 256, 0, stream>>>(W1, Wpk1);
  packW_kernel<128, 64><<<4, 256, 0, stream>>>(W2, Wpk2);

  // CSR build: bucketed counting sort (no per-edge global atomics)
  initcur_kernel<<<1, 256, 0, stream>>>(gcur);
  bin_kernel<<<(E + 2047) / 2048, 256, 0, stream>>>(rowp, colp, ew, gcur, binned, E);
  bdeg_kernel<<<NBUCK, 256, 0, stream>>>(binned, gcur, dinv, cntg, N);
  bscan_kernel<<<1, 256, 0, stream>>>(gcur, bbase);
  csrfill_kernel<<<NBUCK, 256, 0, stream>>>(binned, gcur, bbase, dinv, cntg, start, csr, N);

  // layer 1: MFMA GEMM (f32 A) -> bf16 h1; gather (+bias+relu) -> bf16 h1r
  mfma_gemm_kernel<256, 128, false><<<(N + 127) / 128, 256, 0, stream>>>(x, Wpk1, h1, N);
  gather_kernel<128, true, true><<<(N + 15) / 16, 256, 0, stream>>>(h1, dinv, b1, start, csr,
                                                                    h1r, N, E);

  // layer 2: MFMA GEMM (bf16 A) -> bf16 h2; gather (+bias) -> f32 out
  mfma_gemm_kernel<128, 64, true><<<(N + 127) / 128, 256, 0, stream>>>(h1r, Wpk2, h2, N);
  gather_kernel<64, false, false><<<(N + 31) / 32, 256, 0, stream>>>(h2, dinv, b2, start, csr,
                                                                     outp, N, E);
}